// Round 10
// baseline (382.831 us; speedup 1.0000x reference)
//
#include <hip/hip_runtime.h>
#include <hip/hip_fp16.h>
#include <cstdint>

// GCN: chunk-local bucket partition -> per-bucket LDS counting-sort to CSR ->
// two fused gather-aggregate kernels (layer GEMV + head fused into epilogues).
// Only one standalone GEMM remains (x @ W1, fp32 vector, proven r7 kernel).

constexpr int CHUNK = 8192;   // edges per partition chunk
constexpr int BKCAP = 8192;   // max edges per 128-node bucket (mean 4096)

// ---- P2: per-chunk bucket sort into pairs1 (chunk-grouped, packed 4B) ----
__global__ __launch_bounds__(256) void p2_localsort(
        const int* __restrict__ esrc, const int* __restrict__ edst, int E,
        unsigned* __restrict__ pairs1, int* __restrict__ cntMat,
        int* __restrict__ startMat, int NBK) {
    __shared__ int hist[1024];
    __shared__ int wsum[256];
    __shared__ unsigned lp[CHUNK];        // 32 KB
    const int t = threadIdx.x, blk = blockIdx.x;
    const int base = blk * CHUNK;
    const int cnt = min(CHUNK, E - base);
    for (int i = t; i < 1024; i += 256) hist[i] = 0;
    __syncthreads();
    for (int i = t; i < cnt; i += 256) atomicAdd(&hist[edst[base + i] >> 7], 1);
    __syncthreads();
    int h0 = hist[4*t], h1 = hist[4*t+1], h2 = hist[4*t+2], h3 = hist[4*t+3];
    int s = h0 + h1 + h2 + h3;
    wsum[t] = s; __syncthreads();
    #pragma unroll
    for (int o = 1; o < 256; o <<= 1) {
        int x = (t >= o) ? wsum[t - o] : 0;
        __syncthreads(); wsum[t] += x; __syncthreads();
    }
    int run = wsum[t] - s;
    int e0 = run, e1 = run + h0, e2 = e1 + h1, e3 = e2 + h2;
    hist[4*t] = e0; hist[4*t+1] = e1; hist[4*t+2] = e2; hist[4*t+3] = e3;
    if (4*t     < NBK) { cntMat[(size_t)blk*NBK + 4*t]     = h0; startMat[(size_t)blk*NBK + 4*t]     = e0; }
    if (4*t + 1 < NBK) { cntMat[(size_t)blk*NBK + 4*t + 1] = h1; startMat[(size_t)blk*NBK + 4*t + 1] = e1; }
    if (4*t + 2 < NBK) { cntMat[(size_t)blk*NBK + 4*t + 2] = h2; startMat[(size_t)blk*NBK + 4*t + 2] = e2; }
    if (4*t + 3 < NBK) { cntMat[(size_t)blk*NBK + 4*t + 3] = h3; startMat[(size_t)blk*NBK + 4*t + 3] = e3; }
    __syncthreads();
    for (int i = t; i < cnt; i += 256) {
        int d = edst[base + i];
        int pos = atomicAdd(&hist[d >> 7], 1);
        lp[pos] = ((unsigned)(d & 127) << 17) | (unsigned)esrc[base + i];
    }
    __syncthreads();
    for (int i = t; i < cnt; i += 256) pairs1[base + i] = lp[i];  // coalesced
}

// ---- P3: column-wise exclusive scan of cntMat over chunks; totals -> TB ----
__global__ __launch_bounds__(256) void p3_colscan(int* __restrict__ cntMat,
        int* __restrict__ TB, int nchunks, int NBK) {
    __shared__ int buf[512];
    const int t = threadIdx.x, b = blockIdx.x;
    int v0 = (t < nchunks) ? cntMat[(size_t)t*NBK + b] : 0;
    int v1 = (t + 256 < nchunks) ? cntMat[(size_t)(t + 256)*NBK + b] : 0;
    buf[t] = v0; buf[t + 256] = v1; __syncthreads();
    #pragma unroll
    for (int o = 1; o < 512; o <<= 1) {
        int x0 = (t >= o) ? buf[t - o] : 0;
        int x1 = (t + 256 >= o) ? buf[t + 256 - o] : 0;
        __syncthreads(); buf[t] += x0; buf[t + 256] += x1; __syncthreads();
    }
    if (t < nchunks) cntMat[(size_t)t*NBK + b] = buf[t] - v0;          // cumBefore
    if (t + 256 < nchunks) cntMat[(size_t)(t + 256)*NBK + b] = buf[t + 256] - v1;
    if (t == 0) TB[b] = buf[511];
}

// ---- P4: exclusive scan of TB -> bucketBase ----
__global__ __launch_bounds__(256) void p4_scan(const int* __restrict__ TB,
        int* __restrict__ bucketBase, int NBK, int E) {
    __shared__ int buf[1024];
    __shared__ int wsum[256];
    const int t = threadIdx.x;
    for (int i = t; i < 1024; i += 256) buf[i] = (i < NBK) ? TB[i] : 0;
    __syncthreads();
    int h0 = buf[4*t], h1 = buf[4*t+1], h2 = buf[4*t+2], h3 = buf[4*t+3];
    int s = h0 + h1 + h2 + h3;
    wsum[t] = s; __syncthreads();
    #pragma unroll
    for (int o = 1; o < 256; o <<= 1) {
        int x = (t >= o) ? wsum[t - o] : 0;
        __syncthreads(); wsum[t] += x; __syncthreads();
    }
    int run = wsum[t] - s;
    int e0 = run, e1 = run + h0, e2 = e1 + h1, e3 = e2 + h2;
    if (4*t     < NBK) bucketBase[4*t]     = e0;
    if (4*t + 1 < NBK) bucketBase[4*t + 1] = e1;
    if (4*t + 2 < NBK) bucketBase[4*t + 2] = e2;
    if (4*t + 3 < NBK) bucketBase[4*t + 3] = e3;
    if (t == 0) bucketBase[NBK] = E;
}

// ---- P6: per-bucket gather from pairs1 + LDS counting-sort by node ->
//      csrc (CSR order), rofs[node], dinv[node]. One block per bucket. ----
__global__ __launch_bounds__(256) void p6_sortcsr(
        const unsigned* __restrict__ pairs1, const int* __restrict__ cumMat,
        const int* __restrict__ startMat, const int* __restrict__ TB,
        const int* __restrict__ bucketBase, int nchunks, int NBK,
        int* __restrict__ csrc, int* __restrict__ rofs,
        float* __restrict__ dinv, int N, int E) {
    __shared__ unsigned lp[BKCAP];        // 32 KB
    __shared__ int ccum[512];
    __shared__ int cstart[512];
    __shared__ int hist[128];
    __shared__ int sc[128];
    __shared__ int foffs[128];
    const int t = threadIdx.x, b = blockIdx.x;
    const int total0 = TB[b];
    const int total = min(total0, BKCAP);
    const int base = bucketBase[b];
    for (int i = t; i < nchunks; i += 256) {
        ccum[i]   = cumMat[(size_t)i * NBK + b];
        cstart[i] = startMat[(size_t)i * NBK + b];
    }
    if (t < 128) hist[t] = 0;
    if (t == 0) ccum[nchunks] = total0;
    __syncthreads();
    for (int i = t; i < total; i += 256) {
        int lo = 0, hi = nchunks - 1;
        while (lo < hi) {
            int mid = (lo + hi + 1) >> 1;
            if (ccum[mid] <= i) lo = mid; else hi = mid - 1;
        }
        unsigned v = pairs1[(size_t)lo * CHUNK + cstart[lo] + (i - ccum[lo])];
        lp[i] = v;
        atomicAdd(&hist[v >> 17], 1);
    }
    __syncthreads();
    if (t < 128) sc[t] = hist[t];
    __syncthreads();
    #pragma unroll
    for (int o = 1; o < 128; o <<= 1) {
        int x = (t >= o && t < 128) ? sc[t - o] : 0;
        __syncthreads();
        if (t < 128) sc[t] += x;
        __syncthreads();
    }
    if (t < 128) {
        int excl = sc[t] - hist[t];
        foffs[t] = excl;
        int node = b * 128 + t;
        if (node < N) {
            rofs[node] = base + excl;
            dinv[node] = rsqrtf((float)hist[t] + 1.0f);   // +1 self-loop
        }
    }
    if (b == 0 && t == 255) rofs[N] = E;
    __syncthreads();
    for (int i = t; i < total; i += 256) {
        unsigned v = lp[i];
        int pos = atomicAdd(&foffs[v >> 17], 1);
        csrc[base + pos] = (int)(v & 0x1FFFFu);
    }
}

// ---- GEMM1 (r7, proven): G[row,:] = fp16((X[row,:] @ W1) * dinv[row]) ----
// 64x64 tile, 256 threads, 4x4 thread tile, BK=32; transposed+XOR-swizzled Xs.
template<int K>
__global__ __launch_bounds__(256) void k_gemm(const float* __restrict__ X,
        const float* __restrict__ Wm, const float* __restrict__ dinv,
        __half* __restrict__ G, int nrows) {
    constexpr int BK = 32;
    constexpr int NCH = K / BK;
    constexpr int XP = 68;
    __shared__ float Xs[BK * XP];
    __shared__ float Ws[BK * 64];
    const int t = threadIdx.x;
    const int cg = t & 15;
    const int rg = t >> 4;
    const int brow = blockIdx.x * 64;

    float acc[4][4];
    #pragma unroll
    for (int r = 0; r < 4; ++r)
        #pragma unroll
        for (int c = 0; c < 4; ++c) acc[r][c] = 0.f;

    for (int ch = 0; ch < NCH; ++ch) {
        if (ch) __syncthreads();
        #pragma unroll
        for (int i = 0; i < 2; ++i) {
            int f = t + i * 256;
            int r = f >> 3, c4 = f & 7;
            int gr = brow + r;
            float4 v = make_float4(0.f, 0.f, 0.f, 0.f);
            if (gr < nrows)
                v = *(const float4*)(X + (size_t)gr * K + ch * BK + c4 * 4);
            int rsw = r ^ (c4 << 2);
            Xs[(c4 * 4 + 0) * XP + rsw] = v.x;
            Xs[(c4 * 4 + 1) * XP + rsw] = v.y;
            Xs[(c4 * 4 + 2) * XP + rsw] = v.z;
            Xs[(c4 * 4 + 3) * XP + rsw] = v.w;
        }
        #pragma unroll
        for (int i = 0; i < 2; ++i) {
            int f = t + i * 256;
            int k = f >> 4, c4 = f & 15;
            *(float4*)(Ws + k * 64 + c4 * 4) =
                *(const float4*)(Wm + (size_t)(ch * BK + k) * 64 + c4 * 4);
        }
        __syncthreads();

        #pragma unroll
        for (int k = 0; k < BK; ++k) {
            const int xsw = (k >> 2) << 2;
            float4 xa = *(const float4*)(Xs + k * XP + ((rg * 4) ^ xsw));
            float4 wv = *(const float4*)(Ws + k * 64 + cg * 4);
            acc[0][0] += xa.x * wv.x; acc[0][1] += xa.x * wv.y;
            acc[0][2] += xa.x * wv.z; acc[0][3] += xa.x * wv.w;
            acc[1][0] += xa.y * wv.x; acc[1][1] += xa.y * wv.y;
            acc[1][2] += xa.y * wv.z; acc[1][3] += xa.y * wv.w;
            acc[2][0] += xa.z * wv.x; acc[2][1] += xa.z * wv.y;
            acc[2][2] += xa.z * wv.z; acc[2][3] += xa.z * wv.w;
            acc[3][0] += xa.w * wv.x; acc[3][1] += xa.w * wv.y;
            acc[3][2] += xa.w * wv.z; acc[3][3] += xa.w * wv.w;
        }
    }
    #pragma unroll
    for (int r = 0; r < 4; ++r) {
        int gr = brow + rg * 4 + r;
        if (gr < nrows) {
            float dv = dinv[gr];
            __half2 h01 = __floats2half2_rn(acc[r][0] * dv, acc[r][1] * dv);
            __half2 h23 = __floats2half2_rn(acc[r][2] * dv, acc[r][3] * dv);
            uint2 pk;
            pk.x = *(unsigned*)&h01; pk.y = *(unsigned*)&h23;
            *(uint2*)(G + (size_t)gr * 64 + cg * 4) = pk;
        }
    }
}

// ---- shared gather core: fp16-packed sum over CSR[d] into ha[4] ----
#define ACC8H(HA, V) { \
    HA[0] = __hadd2(HA[0], *(const __half2*)&(V).x); \
    HA[1] = __hadd2(HA[1], *(const __half2*)&(V).y); \
    HA[2] = __hadd2(HA[2], *(const __half2*)&(V).z); \
    HA[3] = __hadd2(HA[3], *(const __half2*)&(V).w); }

#define GATHER_REDUCE(G_, beg_, end_, g_, p_, HA) { \
    int e = (beg_) + (g_); \
    for (; e + 8 < (end_); e += 16) { \
        int s0 = csrc[e]; \
        int s1 = csrc[e + 8]; \
        uint4 v0 = *(const uint4*)((G_) + (size_t)s0 * 64 + (p_) * 8); \
        uint4 v1 = *(const uint4*)((G_) + (size_t)s1 * 64 + (p_) * 8); \
        ACC8H(HA, v0) \
        ACC8H(HA, v1) \
    } \
    if (e < (end_)) { \
        int s = csrc[e]; \
        uint4 v = *(const uint4*)((G_) + (size_t)s * 64 + (p_) * 8); \
        ACC8H(HA, v) \
    } \
    _Pragma("unroll") \
    for (int off = 8; off <= 32; off <<= 1) { \
        _Pragma("unroll") \
        for (int q = 0; q < 4; ++q) { \
            int o = __shfl_xor(*(int*)&HA[q], off); \
            HA[q] = __hadd2(HA[q], *(__half2*)&o); \
        } \
    } }

// ---- agg layer 1 + fused W2 GEMV: G2[d,:] = fp16((relu(conv1) @ W2) * dinv) ----
__global__ __launch_bounds__(256) void k_agg_mid(const __half* __restrict__ G,
        const int* __restrict__ rofs, const int* __restrict__ csrc,
        const float* __restrict__ dinv, const float* __restrict__ b1,
        const float* __restrict__ W2, __half* __restrict__ G2, int nrows) {
    __shared__ float W2s[64 * 64];         // 16 KB, row-major [k][c]
    const int t = threadIdx.x;
    for (int i = t; i < 1024; i += 256)
        ((float4*)W2s)[i] = ((const float4*)W2)[i];
    __syncthreads();
    const int l = t & 63;
    const int g = l >> 3;                  // edge slot
    const int p = l & 7;                   // feature chunk
    const int d = blockIdx.x * 4 + (t >> 6);
    if (d >= nrows) return;                // wave-uniform, no barriers after
    const int beg = rofs[d], end = rofs[d + 1];
    __half2 ha[4];
    #pragma unroll
    for (int q = 0; q < 4; ++q) ha[q] = __half2(__float2half(0.f), __float2half(0.f));
    GATHER_REDUCE(G, beg, end, g, p, ha)

    // h1[j] = relu((sum + self)*dinv + b1), feats p*8+j, all lanes
    uint4 sv = *(const uint4*)(G + (size_t)d * 64 + p * 8);
    const float dv = dinv[d];
    float4 bb0 = *(const float4*)(b1 + p * 8);
    float4 bb1 = *(const float4*)(b1 + p * 8 + 4);
    float2 a0 = __half22float2(ha[0]), a1 = __half22float2(ha[1]);
    float2 a2 = __half22float2(ha[2]), a3 = __half22float2(ha[3]);
    float2 s0 = __half22float2(*(const __half2*)&sv.x);
    float2 s1 = __half22float2(*(const __half2*)&sv.y);
    float2 s2 = __half22float2(*(const __half2*)&sv.z);
    float2 s3 = __half22float2(*(const __half2*)&sv.w);
    float h1[8];
    h1[0] = fmaxf((a0.x + s0.x) * dv + bb0.x, 0.f);
    h1[1] = fmaxf((a0.y + s0.y) * dv + bb0.y, 0.f);
    h1[2] = fmaxf((a1.x + s1.x) * dv + bb0.z, 0.f);
    h1[3] = fmaxf((a1.y + s1.y) * dv + bb0.w, 0.f);
    h1[4] = fmaxf((a2.x + s2.x) * dv + bb1.x, 0.f);
    h1[5] = fmaxf((a2.y + s2.y) * dv + bb1.y, 0.f);
    h1[6] = fmaxf((a3.x + s3.x) * dv + bb1.z, 0.f);
    h1[7] = fmaxf((a3.y + s3.y) * dv + bb1.w, 0.f);

    // GEMV: lane l computes column l of h1 @ W2, scaled by dinv
    float acc = 0.f;
    #pragma unroll
    for (int k = 0; k < 64; ++k) {
        float hk = __shfl(h1[k & 7], k >> 3);
        acc += hk * W2s[k * 64 + l];
    }
    G2[(size_t)d * 64 + l] = __float2half(acc * dv);   // 128B coalesced
}

// ---- agg layer 2 + fused head: out[d,:] = log_softmax(relu(conv2) @ W3 + b3) ----
__global__ __launch_bounds__(256) void k_agg_out(const __half* __restrict__ G2,
        const int* __restrict__ rofs, const int* __restrict__ csrc,
        const float* __restrict__ dinv, const float* __restrict__ b2,
        const float* __restrict__ W3, const float* __restrict__ b3,
        float* __restrict__ out, int nrows) {
    __shared__ float W3s[64 * 40 + 64];    // pad: lanes >=40 read in-bounds junk
    __shared__ float b3s[64];
    const int t = threadIdx.x;
    for (int i = t; i < 640; i += 256)
        ((float4*)W3s)[i] = ((const float4*)W3)[i];
    if (t < 64) b3s[t] = (t < 40) ? b3[t] : 0.f;
    if (t >= 64 && t < 128) W3s[64 * 40 + (t - 64)] = 0.f;
    __syncthreads();
    const int l = t & 63;
    const int g = l >> 3;
    const int p = l & 7;
    const int d = blockIdx.x * 4 + (t >> 6);
    if (d >= nrows) return;                // wave-uniform
    const int beg = rofs[d], end = rofs[d + 1];
    __half2 ha[4];
    #pragma unroll
    for (int q = 0; q < 4; ++q) ha[q] = __half2(__float2half(0.f), __float2half(0.f));
    GATHER_REDUCE(G2, beg, end, g, p, ha)

    uint4 sv = *(const uint4*)(G2 + (size_t)d * 64 + p * 8);
    const float dv = dinv[d];
    float4 bb0 = *(const float4*)(b2 + p * 8);
    float4 bb1 = *(const float4*)(b2 + p * 8 + 4);
    float2 a0 = __half22float2(ha[0]), a1 = __half22float2(ha[1]);
    float2 a2 = __half22float2(ha[2]), a3 = __half22float2(ha[3]);
    float2 s0 = __half22float2(*(const __half2*)&sv.x);
    float2 s1 = __half22float2(*(const __half2*)&sv.y);
    float2 s2 = __half22float2(*(const __half2*)&sv.z);
    float2 s3 = __half22float2(*(const __half2*)&sv.w);
    float h2[8];
    h2[0] = fmaxf((a0.x + s0.x) * dv + bb0.x, 0.f);
    h2[1] = fmaxf((a0.y + s0.y) * dv + bb0.y, 0.f);
    h2[2] = fmaxf((a1.x + s1.x) * dv + bb0.z, 0.f);
    h2[3] = fmaxf((a1.y + s1.y) * dv + bb0.w, 0.f);
    h2[4] = fmaxf((a2.x + s2.x) * dv + bb1.x, 0.f);
    h2[5] = fmaxf((a2.y + s2.y) * dv + bb1.y, 0.f);
    h2[6] = fmaxf((a3.x + s3.x) * dv + bb1.z, 0.f);
    h2[7] = fmaxf((a3.y + s3.y) * dv + bb1.w, 0.f);

    // GEMV: lane l (<40) computes logit l = h2 @ W3[:,l] + b3[l]
    float acc = b3s[l];
    #pragma unroll
    for (int k = 0; k < 64; ++k) {
        float hk = __shfl(h2[k & 7], k >> 3);
        acc += hk * W3s[k * 40 + l];
    }
    // log_softmax over lanes 0..39
    float v = (l < 40) ? acc : -3.4e38f;
    float m = v;
    #pragma unroll
    for (int off = 1; off < 64; off <<= 1) m = fmaxf(m, __shfl_xor(m, off));
    float ex = (l < 40) ? expf(v - m) : 0.f;
    float ssum = ex;
    #pragma unroll
    for (int off = 1; off < 64; off <<= 1) ssum += __shfl_xor(ssum, off);
    float lse = m + logf(ssum);
    if (l < 40) out[(size_t)d * 40 + l] = acc - lse;
}

extern "C" void kernel_launch(void* const* d_in, const int* in_sizes, int n_in,
                              void* d_out, int out_size, void* d_ws, size_t ws_size,
                              hipStream_t stream) {
    const float* x  = (const float*)d_in[0];
    const int*   ei = (const int*)d_in[1];     // [2][E]: row0=src, row1=dst
    const float* W1 = (const float*)d_in[2];
    const float* b1 = (const float*)d_in[3];
    const float* W2 = (const float*)d_in[4];
    const float* b2 = (const float*)d_in[5];
    const float* W3 = (const float*)d_in[6];
    const float* b3 = (const float*)d_in[7];
    float* out = (float*)d_out;

    const int HID = in_sizes[3];            // 64
    const int IND = in_sizes[2] / HID;      // 256
    const int N   = in_sizes[0] / IND;      // 100000
    const int E   = in_sizes[1] / 2;        // 3200000
    (void)HID; (void)n_in; (void)out_size; (void)ws_size;

    const int NBK     = (N + 127) >> 7;             // 782
    const int nchunks = (E + CHUNK - 1) / CHUNK;    // 391

    char* ws = (char*)d_ws;
    size_t off = 0;
    auto alloc = [&](size_t bytes) -> char* {
        char* p = ws + off;
        off = (off + bytes + 255) & ~(size_t)255;
        return p;
    };
    size_t gbytes = (size_t)N * 64 * 2;             // fp16 G
    size_t p1bytes = (size_t)E * 4;                 // pairs1 overlay
    int*      cntMat     = (int*)     alloc((size_t)nchunks * NBK * 4);
    int*      startMat   = (int*)     alloc((size_t)nchunks * NBK * 4);
    int*      TB         = (int*)     alloc((size_t)NBK * 4);
    int*      bucketBase = (int*)     alloc(((size_t)NBK + 1) * 4);
    float*    dinv       = (float*)   alloc((size_t)N * 4);
    int*      rofs       = (int*)     alloc(((size_t)N + 1) * 4);
    int*      csrc       = (int*)     alloc((size_t)E * 4);
    __half*   g          = (__half*)  alloc(gbytes > p1bytes ? gbytes : p1bytes);
    __half*   g2         = (__half*)  alloc(gbytes);
    unsigned* pairs1     = (unsigned*)g;    // overlay: dead before gemm1 writes g

    const int* esrc = ei;
    const int* edst = ei + E;
    const int gM = (N + 63) / 64;           // 1563
    const int gA = (N + 3) / 4;             // 25000

    p2_localsort<<<nchunks, 256, 0, stream>>>(esrc, edst, E, pairs1, cntMat, startMat, NBK);
    p3_colscan  <<<NBK, 256, 0, stream>>>(cntMat, TB, nchunks, NBK);
    p4_scan     <<<1, 256, 0, stream>>>(TB, bucketBase, NBK, E);
    p6_sortcsr  <<<NBK, 256, 0, stream>>>(pairs1, cntMat, startMat, TB, bucketBase,
                                          nchunks, NBK, csrc, rofs, dinv, N, E);

    k_gemm<256> <<<gM, 256, 0, stream>>>(x, W1, dinv, g, N);
    k_agg_mid   <<<gA, 256, 0, stream>>>(g, rofs, csrc, dinv, b1, W2, g2, N);
    k_agg_out   <<<gA, 256, 0, stream>>>(g2, rofs, csrc, dinv, b2, W3, b3, out, N);
}

// Round 11
// 300.643 us; speedup vs baseline: 1.2734x; 1.2734x over previous
//
#include <hip/hip_runtime.h>
#include <hip/hip_fp16.h>
#include <cstdint>

// GCN: partition -> CSR; gemm1 (fp32 tile, fp16 out); two fused gather kernels:
// gather (fp16-packed) -> per-block 16-node MFMA vs W2 / W3(+log_softmax).

constexpr int CHUNK = 8192;
constexpr int BKCAP = 8192;

typedef __attribute__((ext_vector_type(8))) short bf16x8;
typedef __attribute__((ext_vector_type(4))) float f32x4;

__device__ __forceinline__ int cvt2bf(float a, float b) {
    int r;
    asm("v_cvt_pk_bf16_f32 %0, %1, %2" : "=v"(r) : "v"(a), "v"(b));
    return r;
}
__device__ __forceinline__ unsigned short bf16_1(float a) {
    return (unsigned short)(cvt2bf(a, a) & 0xFFFF);
}

// ---- P2: per-chunk bucket sort into pairs1 (chunk-grouped, packed 4B) ----
__global__ __launch_bounds__(256) void p2_localsort(
        const int* __restrict__ esrc, const int* __restrict__ edst, int E,
        unsigned* __restrict__ pairs1, int* __restrict__ cntMat,
        int* __restrict__ startMat, int NBK) {
    __shared__ int hist[1024];
    __shared__ int wsum[256];
    __shared__ unsigned lp[CHUNK];
    const int t = threadIdx.x, blk = blockIdx.x;
    const int base = blk * CHUNK;
    const int cnt = min(CHUNK, E - base);
    for (int i = t; i < 1024; i += 256) hist[i] = 0;
    __syncthreads();
    for (int i = t; i < cnt; i += 256) atomicAdd(&hist[edst[base + i] >> 7], 1);
    __syncthreads();
    int h0 = hist[4*t], h1 = hist[4*t+1], h2 = hist[4*t+2], h3 = hist[4*t+3];
    int s = h0 + h1 + h2 + h3;
    wsum[t] = s; __syncthreads();
    #pragma unroll
    for (int o = 1; o < 256; o <<= 1) {
        int x = (t >= o) ? wsum[t - o] : 0;
        __syncthreads(); wsum[t] += x; __syncthreads();
    }
    int run = wsum[t] - s;
    int e0 = run, e1 = run + h0, e2 = e1 + h1, e3 = e2 + h2;
    hist[4*t] = e0; hist[4*t+1] = e1; hist[4*t+2] = e2; hist[4*t+3] = e3;
    if (4*t     < NBK) { cntMat[(size_t)blk*NBK + 4*t]     = h0; startMat[(size_t)blk*NBK + 4*t]     = e0; }
    if (4*t + 1 < NBK) { cntMat[(size_t)blk*NBK + 4*t + 1] = h1; startMat[(size_t)blk*NBK + 4*t + 1] = e1; }
    if (4*t + 2 < NBK) { cntMat[(size_t)blk*NBK + 4*t + 2] = h2; startMat[(size_t)blk*NBK + 4*t + 2] = e2; }
    if (4*t + 3 < NBK) { cntMat[(size_t)blk*NBK + 4*t + 3] = h3; startMat[(size_t)blk*NBK + 4*t + 3] = e3; }
    __syncthreads();
    for (int i = t; i < cnt; i += 256) {
        int d = edst[base + i];
        int pos = atomicAdd(&hist[d >> 7], 1);
        lp[pos] = ((unsigned)(d & 127) << 17) | (unsigned)esrc[base + i];
    }
    __syncthreads();
    for (int i = t; i < cnt; i += 256) pairs1[base + i] = lp[i];
}

// ---- P3: column-wise exclusive scan of cntMat over chunks; totals -> TB ----
__global__ __launch_bounds__(256) void p3_colscan(int* __restrict__ cntMat,
        int* __restrict__ TB, int nchunks, int NBK) {
    __shared__ int buf[512];
    const int t = threadIdx.x, b = blockIdx.x;
    int v0 = (t < nchunks) ? cntMat[(size_t)t*NBK + b] : 0;
    int v1 = (t + 256 < nchunks) ? cntMat[(size_t)(t + 256)*NBK + b] : 0;
    buf[t] = v0; buf[t + 256] = v1; __syncthreads();
    #pragma unroll
    for (int o = 1; o < 512; o <<= 1) {
        int x0 = (t >= o) ? buf[t - o] : 0;
        int x1 = (t + 256 >= o) ? buf[t + 256 - o] : 0;
        __syncthreads(); buf[t] += x0; buf[t + 256] += x1; __syncthreads();
    }
    if (t < nchunks) cntMat[(size_t)t*NBK + b] = buf[t] - v0;
    if (t + 256 < nchunks) cntMat[(size_t)(t + 256)*NBK + b] = buf[t + 256] - v1;
    if (t == 0) TB[b] = buf[511];
}

// ---- P4: exclusive scan of TB -> bucketBase ----
__global__ __launch_bounds__(256) void p4_scan(const int* __restrict__ TB,
        int* __restrict__ bucketBase, int NBK, int E) {
    __shared__ int buf[1024];
    __shared__ int wsum[256];
    const int t = threadIdx.x;
    for (int i = t; i < 1024; i += 256) buf[i] = (i < NBK) ? TB[i] : 0;
    __syncthreads();
    int h0 = buf[4*t], h1 = buf[4*t+1], h2 = buf[4*t+2], h3 = buf[4*t+3];
    int s = h0 + h1 + h2 + h3;
    wsum[t] = s; __syncthreads();
    #pragma unroll
    for (int o = 1; o < 256; o <<= 1) {
        int x = (t >= o) ? wsum[t - o] : 0;
        __syncthreads(); wsum[t] += x; __syncthreads();
    }
    int run = wsum[t] - s;
    int e0 = run, e1 = run + h0, e2 = e1 + h1, e3 = e2 + h2;
    if (4*t     < NBK) bucketBase[4*t]     = e0;
    if (4*t + 1 < NBK) bucketBase[4*t + 1] = e1;
    if (4*t + 2 < NBK) bucketBase[4*t + 2] = e2;
    if (4*t + 3 < NBK) bucketBase[4*t + 3] = e3;
    if (t == 0) bucketBase[NBK] = E;
}

// ---- P6: per-bucket gather + LDS counting-sort -> csrc/rofs/dinv ----
__global__ __launch_bounds__(256) void p6_sortcsr(
        const unsigned* __restrict__ pairs1, const int* __restrict__ cumMat,
        const int* __restrict__ startMat, const int* __restrict__ TB,
        const int* __restrict__ bucketBase, int nchunks, int NBK,
        int* __restrict__ csrc, int* __restrict__ rofs,
        float* __restrict__ dinv, int N, int E) {
    __shared__ unsigned lp[BKCAP];
    __shared__ int ccum[512];
    __shared__ int cstart[512];
    __shared__ int hist[128];
    __shared__ int sc[128];
    __shared__ int foffs[128];
    const int t = threadIdx.x, b = blockIdx.x;
    const int total0 = TB[b];
    const int total = min(total0, BKCAP);
    const int base = bucketBase[b];
    for (int i = t; i < nchunks; i += 256) {
        ccum[i]   = cumMat[(size_t)i * NBK + b];
        cstart[i] = startMat[(size_t)i * NBK + b];
    }
    if (t < 128) hist[t] = 0;
    if (t == 0) ccum[nchunks] = total0;
    __syncthreads();
    for (int i = t; i < total; i += 256) {
        int lo = 0, hi = nchunks - 1;
        while (lo < hi) {
            int mid = (lo + hi + 1) >> 1;
            if (ccum[mid] <= i) lo = mid; else hi = mid - 1;
        }
        unsigned v = pairs1[(size_t)lo * CHUNK + cstart[lo] + (i - ccum[lo])];
        lp[i] = v;
        atomicAdd(&hist[v >> 17], 1);
    }
    __syncthreads();
    if (t < 128) sc[t] = hist[t];
    __syncthreads();
    #pragma unroll
    for (int o = 1; o < 128; o <<= 1) {
        int x = (t >= o && t < 128) ? sc[t - o] : 0;
        __syncthreads();
        if (t < 128) sc[t] += x;
        __syncthreads();
    }
    if (t < 128) {
        int excl = sc[t] - hist[t];
        foffs[t] = excl;
        int node = b * 128 + t;
        if (node < N) {
            rofs[node] = base + excl;
            dinv[node] = rsqrtf((float)hist[t] + 1.0f);
        }
    }
    if (b == 0 && t == 255) rofs[N] = E;
    __syncthreads();
    for (int i = t; i < total; i += 256) {
        unsigned v = lp[i];
        int pos = atomicAdd(&foffs[v >> 17], 1);
        csrc[base + pos] = (int)(v & 0x1FFFFu);
    }
}

// ---- GEMM1 (proven r7): G[row,:] = fp16((X @ W1) * dinv), fp32 vector ----
template<int K>
__global__ __launch_bounds__(256) void k_gemm(const float* __restrict__ X,
        const float* __restrict__ Wm, const float* __restrict__ dinv,
        __half* __restrict__ G, int nrows) {
    constexpr int BK = 32;
    constexpr int NCH = K / BK;
    constexpr int XP = 68;
    __shared__ float Xs[BK * XP];
    __shared__ float Ws[BK * 64];
    const int t = threadIdx.x;
    const int cg = t & 15;
    const int rg = t >> 4;
    const int brow = blockIdx.x * 64;

    float acc[4][4];
    #pragma unroll
    for (int r = 0; r < 4; ++r)
        #pragma unroll
        for (int c = 0; c < 4; ++c) acc[r][c] = 0.f;

    for (int ch = 0; ch < NCH; ++ch) {
        if (ch) __syncthreads();
        #pragma unroll
        for (int i = 0; i < 2; ++i) {
            int f = t + i * 256;
            int r = f >> 3, c4 = f & 7;
            int gr = brow + r;
            float4 v = make_float4(0.f, 0.f, 0.f, 0.f);
            if (gr < nrows)
                v = *(const float4*)(X + (size_t)gr * K + ch * BK + c4 * 4);
            int rsw = r ^ (c4 << 2);
            Xs[(c4 * 4 + 0) * XP + rsw] = v.x;
            Xs[(c4 * 4 + 1) * XP + rsw] = v.y;
            Xs[(c4 * 4 + 2) * XP + rsw] = v.z;
            Xs[(c4 * 4 + 3) * XP + rsw] = v.w;
        }
        #pragma unroll
        for (int i = 0; i < 2; ++i) {
            int f = t + i * 256;
            int k = f >> 4, c4 = f & 15;
            *(float4*)(Ws + k * 64 + c4 * 4) =
                *(const float4*)(Wm + (size_t)(ch * BK + k) * 64 + c4 * 4);
        }
        __syncthreads();

        #pragma unroll
        for (int k = 0; k < BK; ++k) {
            const int xsw = (k >> 2) << 2;
            float4 xa = *(const float4*)(Xs + k * XP + ((rg * 4) ^ xsw));
            float4 wv = *(const float4*)(Ws + k * 64 + cg * 4);
            acc[0][0] += xa.x * wv.x; acc[0][1] += xa.x * wv.y;
            acc[0][2] += xa.x * wv.z; acc[0][3] += xa.x * wv.w;
            acc[1][0] += xa.y * wv.x; acc[1][1] += xa.y * wv.y;
            acc[1][2] += xa.y * wv.z; acc[1][3] += xa.y * wv.w;
            acc[2][0] += xa.z * wv.x; acc[2][1] += xa.z * wv.y;
            acc[2][2] += xa.z * wv.z; acc[2][3] += xa.z * wv.w;
            acc[3][0] += xa.w * wv.x; acc[3][1] += xa.w * wv.y;
            acc[3][2] += xa.w * wv.z; acc[3][3] += xa.w * wv.w;
        }
    }
    #pragma unroll
    for (int r = 0; r < 4; ++r) {
        int gr = brow + rg * 4 + r;
        if (gr < nrows) {
            float dv = dinv[gr];
            __half2 h01 = __floats2half2_rn(acc[r][0] * dv, acc[r][1] * dv);
            __half2 h23 = __floats2half2_rn(acc[r][2] * dv, acc[r][3] * dv);
            uint2 pk;
            pk.x = *(unsigned*)&h01; pk.y = *(unsigned*)&h23;
            *(uint2*)(G + (size_t)gr * 64 + cg * 4) = pk;
        }
    }
}

// ---- gather core: fp16-packed sum over CSR[d] into ha[4] (proven r8) ----
#define ACC8H(HA, V) { \
    HA[0] = __hadd2(HA[0], *(const __half2*)&(V).x); \
    HA[1] = __hadd2(HA[1], *(const __half2*)&(V).y); \
    HA[2] = __hadd2(HA[2], *(const __half2*)&(V).z); \
    HA[3] = __hadd2(HA[3], *(const __half2*)&(V).w); }

#define GATHER_REDUCE(G_, beg_, end_, g_, p_, HA) { \
    int e = (beg_) + (g_); \
    for (; e + 8 < (end_); e += 16) { \
        int s0 = csrc[e]; \
        int s1 = csrc[e + 8]; \
        uint4 v0 = *(const uint4*)((G_) + (size_t)s0 * 64 + (p_) * 8); \
        uint4 v1 = *(const uint4*)((G_) + (size_t)s1 * 64 + (p_) * 8); \
        ACC8H(HA, v0) \
        ACC8H(HA, v1) \
    } \
    if (e < (end_)) { \
        int s = csrc[e]; \
        uint4 v = *(const uint4*)((G_) + (size_t)s * 64 + (p_) * 8); \
        ACC8H(HA, v) \
    } \
    _Pragma("unroll") \
    for (int off = 8; off <= 32; off <<= 1) { \
        _Pragma("unroll") \
        for (int q = 0; q < 4; ++q) { \
            int o = __shfl_xor(*(int*)&HA[q], off); \
            HA[q] = __hadd2(HA[q], *(__half2*)&o); \
        } \
    } }

// epilogue: h[8] = relu((sum+self)*dv + bias[p*8..]) for this lane's chunk
#define CONV_EPILOGUE(G_, d_, dv_, bias_, p_, HA, HOUT) { \
    uint4 sv = *(const uint4*)((G_) + (size_t)(d_) * 64 + (p_) * 8); \
    float4 bb0 = *(const float4*)((bias_) + (p_) * 8); \
    float4 bb1 = *(const float4*)((bias_) + (p_) * 8 + 4); \
    float2 a0 = __half22float2(HA[0]), a1 = __half22float2(HA[1]); \
    float2 a2 = __half22float2(HA[2]), a3 = __half22float2(HA[3]); \
    float2 s0 = __half22float2(*(const __half2*)&sv.x); \
    float2 s1 = __half22float2(*(const __half2*)&sv.y); \
    float2 s2 = __half22float2(*(const __half2*)&sv.z); \
    float2 s3 = __half22float2(*(const __half2*)&sv.w); \
    HOUT[0] = fmaxf((a0.x + s0.x) * (dv_) + bb0.x, 0.f); \
    HOUT[1] = fmaxf((a0.y + s0.y) * (dv_) + bb0.y, 0.f); \
    HOUT[2] = fmaxf((a1.x + s1.x) * (dv_) + bb0.z, 0.f); \
    HOUT[3] = fmaxf((a1.y + s1.y) * (dv_) + bb0.w, 0.f); \
    HOUT[4] = fmaxf((a2.x + s2.x) * (dv_) + bb1.x, 0.f); \
    HOUT[5] = fmaxf((a2.y + s2.y) * (dv_) + bb1.y, 0.f); \
    HOUT[6] = fmaxf((a3.x + s3.x) * (dv_) + bb1.z, 0.f); \
    HOUT[7] = fmaxf((a3.y + s3.y) * (dv_) + bb1.w, 0.f); }

// ---- agg layer1 + MFMA W2: G2[d,:] = fp16((relu(conv1) @ W2) * dinv[d]) ----
// Block = 16 nodes (4 waves x 4 serial). Phase1 gather -> H1s bf16 [16][68].
// Phase2: wave w -> cols w*16..+16, 2x mfma_16x16x32_bf16 vs W2t bf16 [64][68].
__global__ __launch_bounds__(256) void k_agg_mid(const __half* __restrict__ G,
        const int* __restrict__ rofs, const int* __restrict__ csrc,
        const float* __restrict__ dinv, const float* __restrict__ b1,
        const float* __restrict__ W2, __half* __restrict__ G2, int nrows) {
    __shared__ unsigned short W2t[64 * 68];  // bf16 W2^T [col][k]
    __shared__ unsigned short H1s[16 * 68];  // bf16 h1 rows [node][k]
    const int t = threadIdx.x;
    for (int i = t; i < 4096; i += 256) {
        int k = i >> 6, c = i & 63;
        W2t[c * 68 + k] = bf16_1(W2[i]);
    }
    const int l = t & 63;
    const int w = t >> 6;
    const int g = l >> 3, p = l & 7;
    const int nbase = blockIdx.x * 16;
    #pragma unroll 1
    for (int i = 0; i < 4; ++i) {
        int row = w * 4 + i;
        int d = nbase + row;
        if (d < nrows) {
            int beg = rofs[d], end = rofs[d + 1];
            __half2 ha[4];
            #pragma unroll
            for (int q = 0; q < 4; ++q) ha[q] = __half2(__float2half(0.f), __float2half(0.f));
            GATHER_REDUCE(G, beg, end, g, p, ha)
            float dv = dinv[d];
            float h1[8];
            CONV_EPILOGUE(G, d, dv, b1, p, ha, h1)
            if (g == 0) {
                int4 pk;
                pk.x = cvt2bf(h1[0], h1[1]); pk.y = cvt2bf(h1[2], h1[3]);
                pk.z = cvt2bf(h1[4], h1[5]); pk.w = cvt2bf(h1[6], h1[7]);
                *(int4*)(&H1s[row * 68 + p * 8]) = pk;
            }
        }
    }
    __syncthreads();
    // phase 2: D = H1 @ W2 (16x64), wave w owns cols w*16..+16
    const int c16 = l & 15, g4 = l >> 4;
    f32x4 acc = {0.f, 0.f, 0.f, 0.f};
    #pragma unroll
    for (int kc = 0; kc < 2; ++kc) {
        bf16x8 a = *(bf16x8*)(&H1s[c16 * 68 + kc * 32 + g4 * 8]);
        bf16x8 b = *(bf16x8*)(&W2t[(w * 16 + c16) * 68 + kc * 32 + g4 * 8]);
        acc = __builtin_amdgcn_mfma_f32_16x16x32_bf16(a, b, acc, 0, 0, 0);
    }
    #pragma unroll
    for (int r = 0; r < 4; ++r) {
        int d = nbase + g4 * 4 + r;
        if (d < nrows)
            G2[(size_t)d * 64 + w * 16 + c16] = __float2half(acc[r] * dinv[d]);
    }
}

// ---- agg layer2 + MFMA W3 + log_softmax -> out ----
__global__ __launch_bounds__(256) void k_agg_out(const __half* __restrict__ G2,
        const int* __restrict__ rofs, const int* __restrict__ csrc,
        const float* __restrict__ dinv, const float* __restrict__ b2,
        const float* __restrict__ W3, const float* __restrict__ b3,
        float* __restrict__ out, int nrows) {
    constexpr int LP = 49;                   // logits pitch (floats)
    __shared__ unsigned short W3t[48 * 68];  // bf16 W3^T, cols 40..47 zero
    __shared__ unsigned short H2s[16 * 68];
    __shared__ float Ls[16 * LP];
    __shared__ float b3s[48];
    const int t = threadIdx.x;
    for (int i = t; i < 48 * 64; i += 256) {
        int c = i >> 6, k = i & 63;
        W3t[c * 68 + k] = (c < 40) ? bf16_1(W3[k * 40 + c]) : (unsigned short)0;
    }
    if (t < 48) b3s[t] = (t < 40) ? b3[t] : 0.f;
    const int l = t & 63;
    const int w = t >> 6;
    const int g = l >> 3, p = l & 7;
    const int nbase = blockIdx.x * 16;
    #pragma unroll 1
    for (int i = 0; i < 4; ++i) {
        int row = w * 4 + i;
        int d = nbase + row;
        if (d < nrows) {
            int beg = rofs[d], end = rofs[d + 1];
            __half2 ha[4];
            #pragma unroll
            for (int q = 0; q < 4; ++q) ha[q] = __half2(__float2half(0.f), __float2half(0.f));
            GATHER_REDUCE(G2, beg, end, g, p, ha)
            float dv = dinv[d];
            float h2[8];
            CONV_EPILOGUE(G2, d, dv, b2, p, ha, h2)
            if (g == 0) {
                int4 pk;
                pk.x = cvt2bf(h2[0], h2[1]); pk.y = cvt2bf(h2[2], h2[3]);
                pk.z = cvt2bf(h2[4], h2[5]); pk.w = cvt2bf(h2[6], h2[7]);
                *(int4*)(&H2s[row * 68 + p * 8]) = pk;
            }
        }
    }
    __syncthreads();
    // phase 2: logits = H2 @ W3 (16x40, padded 48); waves 0..2 only
    const int c16 = l & 15, g4 = l >> 4;
    if (w < 3) {
        f32x4 acc = {0.f, 0.f, 0.f, 0.f};
        #pragma unroll
        for (int kc = 0; kc < 2; ++kc) {
            bf16x8 a = *(bf16x8*)(&H2s[c16 * 68 + kc * 32 + g4 * 8]);
            bf16x8 b = *(bf16x8*)(&W3t[(w * 16 + c16) * 68 + kc * 32 + g4 * 8]);
            acc = __builtin_amdgcn_mfma_f32_16x16x32_bf16(a, b, acc, 0, 0, 0);
        }
        #pragma unroll
        for (int r = 0; r < 4; ++r)
            Ls[(g4 * 4 + r) * LP + w * 16 + c16] = acc[r] + b3s[w * 16 + c16];
    }
    __syncthreads();
    // phase 3: per-node log_softmax over 40 logits; wave w -> nodes w*4..+4
    #pragma unroll 1
    for (int i = 0; i < 4; ++i) {
        int row = w * 4 + i;
        int d = nbase + row;
        if (d >= nrows) continue;
        float v = (l < 40) ? Ls[row * LP + l] : -3.4e38f;
        float m = v;
        #pragma unroll
        for (int off = 1; off < 64; off <<= 1) m = fmaxf(m, __shfl_xor(m, off));
        float ex = (l < 40) ? expf(v - m) : 0.f;
        float ssum = ex;
        #pragma unroll
        for (int off = 1; off < 64; off <<= 1) ssum += __shfl_xor(ssum, off);
        float lse = m + logf(ssum);
        if (l < 40) out[(size_t)d * 40 + l] = v - lse;
    }
}

extern "C" void kernel_launch(void* const* d_in, const int* in_sizes, int n_in,
                              void* d_out, int out_size, void* d_ws, size_t ws_size,
                              hipStream_t stream) {
    const float* x  = (const float*)d_in[0];
    const int*   ei = (const int*)d_in[1];
    const float* W1 = (const float*)d_in[2];
    const float* b1 = (const float*)d_in[3];
    const float* W2 = (const float*)d_in[4];
    const float* b2 = (const float*)d_in[5];
    const float* W3 = (const float*)d_in[6];
    const float* b3 = (const float*)d_in[7];
    float* out = (float*)d_out;

    const int HID = in_sizes[3];            // 64
    const int IND = in_sizes[2] / HID;      // 256
    const int N   = in_sizes[0] / IND;      // 100000
    const int E   = in_sizes[1] / 2;        // 3200000
    (void)HID; (void)n_in; (void)out_size; (void)ws_size;

    const int NBK     = (N + 127) >> 7;             // 782
    const int nchunks = (E + CHUNK - 1) / CHUNK;    // 391

    char* ws = (char*)d_ws;
    size_t off = 0;
    auto alloc = [&](size_t bytes) -> char* {
        char* p = ws + off;
        off = (off + bytes + 255) & ~(size_t)255;
        return p;
    };
    size_t gbytes = (size_t)N * 64 * 2;             // fp16 G
    size_t p1bytes = (size_t)E * 4;                 // pairs1 overlay
    int*      cntMat     = (int*)     alloc((size_t)nchunks * NBK * 4);
    int*      startMat   = (int*)     alloc((size_t)nchunks * NBK * 4);
    int*      TB         = (int*)     alloc((size_t)NBK * 4);
    int*      bucketBase = (int*)     alloc(((size_t)NBK + 1) * 4);
    float*    dinv       = (float*)   alloc((size_t)N * 4);
    int*      rofs       = (int*)     alloc(((size_t)N + 1) * 4);
    int*      csrc       = (int*)     alloc((size_t)E * 4);
    __half*   g          = (__half*)  alloc(gbytes > p1bytes ? gbytes : p1bytes);
    __half*   g2         = (__half*)  alloc(gbytes);
    unsigned* pairs1     = (unsigned*)g;    // overlay: dead before gemm1 writes g

    const int* esrc = ei;
    const int* edst = ei + E;
    const int gM  = (N + 63) / 64;          // 1563
    const int gA  = (N + 15) / 16;          // 6250

    p2_localsort<<<nchunks, 256, 0, stream>>>(esrc, edst, E, pairs1, cntMat, startMat, NBK);
    p3_colscan  <<<NBK, 256, 0, stream>>>(cntMat, TB, nchunks, NBK);
    p4_scan     <<<1, 256, 0, stream>>>(TB, bucketBase, NBK, E);
    p6_sortcsr  <<<NBK, 256, 0, stream>>>(pairs1, cntMat, startMat, TB, bucketBase,
                                          nchunks, NBK, csrc, rofs, dinv, N, E);

    k_gemm<256> <<<gM, 256, 0, stream>>>(x, W1, dinv, g, N);
    k_agg_mid   <<<gA, 256, 0, stream>>>(g, rofs, csrc, dinv, b1, W2, g2, N);
    k_agg_out   <<<gA, 256, 0, stream>>>(g2, rofs, csrc, dinv, b2, W3, b3, out, N);
}

// Round 12
// 277.009 us; speedup vs baseline: 1.3820x; 1.0853x over previous
//
#include <hip/hip_runtime.h>
#include <hip/hip_fp16.h>
#include <cstdint>

// GCN: partition -> CSR; gemm1 (fp32 tile, fp16 out); two fused gather kernels.
// Gather: 4 nodes per wave CONCURRENT (16 lanes/node, 2 slots x 4-deep) ->
// bf16 h-rows in LDS -> per-block 16-node MFMA vs W2 / W3 (+log_softmax).

constexpr int CHUNK = 8192;
constexpr int BKCAP = 8192;

typedef __attribute__((ext_vector_type(8))) short bf16x8;
typedef __attribute__((ext_vector_type(4))) float f32x4;

__device__ __forceinline__ int cvt2bf(float a, float b) {
    int r;
    asm("v_cvt_pk_bf16_f32 %0, %1, %2" : "=v"(r) : "v"(a), "v"(b));
    return r;
}
__device__ __forceinline__ unsigned short bf16_1(float a) {
    return (unsigned short)(cvt2bf(a, a) & 0xFFFF);
}

// ---- P2: per-chunk bucket sort into pairs1 (chunk-grouped, packed 4B) ----
__global__ __launch_bounds__(256) void p2_localsort(
        const int* __restrict__ esrc, const int* __restrict__ edst, int E,
        unsigned* __restrict__ pairs1, int* __restrict__ cntMat,
        int* __restrict__ startMat, int NBK) {
    __shared__ int hist[1024];
    __shared__ int wsum[256];
    __shared__ unsigned lp[CHUNK];
    const int t = threadIdx.x, blk = blockIdx.x;
    const int base = blk * CHUNK;
    const int cnt = min(CHUNK, E - base);
    for (int i = t; i < 1024; i += 256) hist[i] = 0;
    __syncthreads();
    for (int i = t; i < cnt; i += 256) atomicAdd(&hist[edst[base + i] >> 7], 1);
    __syncthreads();
    int h0 = hist[4*t], h1 = hist[4*t+1], h2 = hist[4*t+2], h3 = hist[4*t+3];
    int s = h0 + h1 + h2 + h3;
    wsum[t] = s; __syncthreads();
    #pragma unroll
    for (int o = 1; o < 256; o <<= 1) {
        int x = (t >= o) ? wsum[t - o] : 0;
        __syncthreads(); wsum[t] += x; __syncthreads();
    }
    int run = wsum[t] - s;
    int e0 = run, e1 = run + h0, e2 = e1 + h1, e3 = e2 + h2;
    hist[4*t] = e0; hist[4*t+1] = e1; hist[4*t+2] = e2; hist[4*t+3] = e3;
    if (4*t     < NBK) { cntMat[(size_t)blk*NBK + 4*t]     = h0; startMat[(size_t)blk*NBK + 4*t]     = e0; }
    if (4*t + 1 < NBK) { cntMat[(size_t)blk*NBK + 4*t + 1] = h1; startMat[(size_t)blk*NBK + 4*t + 1] = e1; }
    if (4*t + 2 < NBK) { cntMat[(size_t)blk*NBK + 4*t + 2] = h2; startMat[(size_t)blk*NBK + 4*t + 2] = e2; }
    if (4*t + 3 < NBK) { cntMat[(size_t)blk*NBK + 4*t + 3] = h3; startMat[(size_t)blk*NBK + 4*t + 3] = e3; }
    __syncthreads();
    for (int i = t; i < cnt; i += 256) {
        int d = edst[base + i];
        int pos = atomicAdd(&hist[d >> 7], 1);
        lp[pos] = ((unsigned)(d & 127) << 17) | (unsigned)esrc[base + i];
    }
    __syncthreads();
    for (int i = t; i < cnt; i += 256) pairs1[base + i] = lp[i];
}

// ---- P3: column-wise exclusive scan of cntMat over chunks; totals -> TB ----
__global__ __launch_bounds__(256) void p3_colscan(int* __restrict__ cntMat,
        int* __restrict__ TB, int nchunks, int NBK) {
    __shared__ int buf[512];
    const int t = threadIdx.x, b = blockIdx.x;
    int v0 = (t < nchunks) ? cntMat[(size_t)t*NBK + b] : 0;
    int v1 = (t + 256 < nchunks) ? cntMat[(size_t)(t + 256)*NBK + b] : 0;
    buf[t] = v0; buf[t + 256] = v1; __syncthreads();
    #pragma unroll
    for (int o = 1; o < 512; o <<= 1) {
        int x0 = (t >= o) ? buf[t - o] : 0;
        int x1 = (t + 256 >= o) ? buf[t + 256 - o] : 0;
        __syncthreads(); buf[t] += x0; buf[t + 256] += x1; __syncthreads();
    }
    if (t < nchunks) cntMat[(size_t)t*NBK + b] = buf[t] - v0;
    if (t + 256 < nchunks) cntMat[(size_t)(t + 256)*NBK + b] = buf[t + 256] - v1;
    if (t == 0) TB[b] = buf[511];
}

// ---- P4: exclusive scan of TB -> bucketBase ----
__global__ __launch_bounds__(256) void p4_scan(const int* __restrict__ TB,
        int* __restrict__ bucketBase, int NBK, int E) {
    __shared__ int buf[1024];
    __shared__ int wsum[256];
    const int t = threadIdx.x;
    for (int i = t; i < 1024; i += 256) buf[i] = (i < NBK) ? TB[i] : 0;
    __syncthreads();
    int h0 = buf[4*t], h1 = buf[4*t+1], h2 = buf[4*t+2], h3 = buf[4*t+3];
    int s = h0 + h1 + h2 + h3;
    wsum[t] = s; __syncthreads();
    #pragma unroll
    for (int o = 1; o < 256; o <<= 1) {
        int x = (t >= o) ? wsum[t - o] : 0;
        __syncthreads(); wsum[t] += x; __syncthreads();
    }
    int run = wsum[t] - s;
    int e0 = run, e1 = run + h0, e2 = e1 + h1, e3 = e2 + h2;
    if (4*t     < NBK) bucketBase[4*t]     = e0;
    if (4*t + 1 < NBK) bucketBase[4*t + 1] = e1;
    if (4*t + 2 < NBK) bucketBase[4*t + 2] = e2;
    if (4*t + 3 < NBK) bucketBase[4*t + 3] = e3;
    if (t == 0) bucketBase[NBK] = E;
}

// ---- P6: per-bucket gather + LDS counting-sort -> csrc/rofs/dinv ----
__global__ __launch_bounds__(256) void p6_sortcsr(
        const unsigned* __restrict__ pairs1, const int* __restrict__ cumMat,
        const int* __restrict__ startMat, const int* __restrict__ TB,
        const int* __restrict__ bucketBase, int nchunks, int NBK,
        int* __restrict__ csrc, int* __restrict__ rofs,
        float* __restrict__ dinv, int N, int E) {
    __shared__ unsigned lp[BKCAP];
    __shared__ int ccum[512];
    __shared__ int cstart[512];
    __shared__ int hist[128];
    __shared__ int sc[128];
    __shared__ int foffs[128];
    const int t = threadIdx.x, b = blockIdx.x;
    const int total0 = TB[b];
    const int total = min(total0, BKCAP);
    const int base = bucketBase[b];
    for (int i = t; i < nchunks; i += 256) {
        ccum[i]   = cumMat[(size_t)i * NBK + b];
        cstart[i] = startMat[(size_t)i * NBK + b];
    }
    if (t < 128) hist[t] = 0;
    if (t == 0) ccum[nchunks] = total0;
    __syncthreads();
    for (int i = t; i < total; i += 256) {
        int lo = 0, hi = nchunks - 1;
        while (lo < hi) {
            int mid = (lo + hi + 1) >> 1;
            if (ccum[mid] <= i) lo = mid; else hi = mid - 1;
        }
        unsigned v = pairs1[(size_t)lo * CHUNK + cstart[lo] + (i - ccum[lo])];
        lp[i] = v;
        atomicAdd(&hist[v >> 17], 1);
    }
    __syncthreads();
    if (t < 128) sc[t] = hist[t];
    __syncthreads();
    #pragma unroll
    for (int o = 1; o < 128; o <<= 1) {
        int x = (t >= o && t < 128) ? sc[t - o] : 0;
        __syncthreads();
        if (t < 128) sc[t] += x;
        __syncthreads();
    }
    if (t < 128) {
        int excl = sc[t] - hist[t];
        foffs[t] = excl;
        int node = b * 128 + t;
        if (node < N) {
            rofs[node] = base + excl;
            dinv[node] = rsqrtf((float)hist[t] + 1.0f);
        }
    }
    if (b == 0 && t == 255) rofs[N] = E;
    __syncthreads();
    for (int i = t; i < total; i += 256) {
        unsigned v = lp[i];
        int pos = atomicAdd(&foffs[v >> 17], 1);
        csrc[base + pos] = (int)(v & 0x1FFFFu);
    }
}

// ---- GEMM1 (proven r7): G[row,:] = fp16((X @ W1) * dinv), fp32 vector ----
template<int K>
__global__ __launch_bounds__(256) void k_gemm(const float* __restrict__ X,
        const float* __restrict__ Wm, const float* __restrict__ dinv,
        __half* __restrict__ G, int nrows) {
    constexpr int BK = 32;
    constexpr int NCH = K / BK;
    constexpr int XP = 68;
    __shared__ float Xs[BK * XP];
    __shared__ float Ws[BK * 64];
    const int t = threadIdx.x;
    const int cg = t & 15;
    const int rg = t >> 4;
    const int brow = blockIdx.x * 64;

    float acc[4][4];
    #pragma unroll
    for (int r = 0; r < 4; ++r)
        #pragma unroll
        for (int c = 0; c < 4; ++c) acc[r][c] = 0.f;

    for (int ch = 0; ch < NCH; ++ch) {
        if (ch) __syncthreads();
        #pragma unroll
        for (int i = 0; i < 2; ++i) {
            int f = t + i * 256;
            int r = f >> 3, c4 = f & 7;
            int gr = brow + r;
            float4 v = make_float4(0.f, 0.f, 0.f, 0.f);
            if (gr < nrows)
                v = *(const float4*)(X + (size_t)gr * K + ch * BK + c4 * 4);
            int rsw = r ^ (c4 << 2);
            Xs[(c4 * 4 + 0) * XP + rsw] = v.x;
            Xs[(c4 * 4 + 1) * XP + rsw] = v.y;
            Xs[(c4 * 4 + 2) * XP + rsw] = v.z;
            Xs[(c4 * 4 + 3) * XP + rsw] = v.w;
        }
        #pragma unroll
        for (int i = 0; i < 2; ++i) {
            int f = t + i * 256;
            int k = f >> 4, c4 = f & 15;
            *(float4*)(Ws + k * 64 + c4 * 4) =
                *(const float4*)(Wm + (size_t)(ch * BK + k) * 64 + c4 * 4);
        }
        __syncthreads();

        #pragma unroll
        for (int k = 0; k < BK; ++k) {
            const int xsw = (k >> 2) << 2;
            float4 xa = *(const float4*)(Xs + k * XP + ((rg * 4) ^ xsw));
            float4 wv = *(const float4*)(Ws + k * 64 + cg * 4);
            acc[0][0] += xa.x * wv.x; acc[0][1] += xa.x * wv.y;
            acc[0][2] += xa.x * wv.z; acc[0][3] += xa.x * wv.w;
            acc[1][0] += xa.y * wv.x; acc[1][1] += xa.y * wv.y;
            acc[1][2] += xa.y * wv.z; acc[1][3] += xa.y * wv.w;
            acc[2][0] += xa.z * wv.x; acc[2][1] += xa.z * wv.y;
            acc[2][2] += xa.z * wv.z; acc[2][3] += xa.z * wv.w;
            acc[3][0] += xa.w * wv.x; acc[3][1] += xa.w * wv.y;
            acc[3][2] += xa.w * wv.z; acc[3][3] += xa.w * wv.w;
        }
    }
    #pragma unroll
    for (int r = 0; r < 4; ++r) {
        int gr = brow + rg * 4 + r;
        if (gr < nrows) {
            float dv = dinv[gr];
            __half2 h01 = __floats2half2_rn(acc[r][0] * dv, acc[r][1] * dv);
            __half2 h23 = __floats2half2_rn(acc[r][2] * dv, acc[r][3] * dv);
            uint2 pk;
            pk.x = *(unsigned*)&h01; pk.y = *(unsigned*)&h23;
            *(uint2*)(G + (size_t)gr * 64 + cg * 4) = pk;
        }
    }
}

// ---- gather helpers ----
#define ACC8H(HA, V) { \
    HA[0] = __hadd2(HA[0], *(const __half2*)&(V).x); \
    HA[1] = __hadd2(HA[1], *(const __half2*)&(V).y); \
    HA[2] = __hadd2(HA[2], *(const __half2*)&(V).z); \
    HA[3] = __hadd2(HA[3], *(const __half2*)&(V).w); }

// per-node-group gather: 16 lanes (2 slots x 8 chunks), 4-deep unroll.
// After the loop, shfl_xor(8) combines the two slots -> all 16 lanes hold sums.
#define GATHER16(G_, beg_, end_, s_, p_, HA) { \
    int e = (beg_) + (s_); \
    for (; e + 6 < (end_); e += 8) { \
        int i0 = csrc[e], i1 = csrc[e + 2], i2 = csrc[e + 4], i3 = csrc[e + 6]; \
        uint4 v0 = *(const uint4*)((G_) + (size_t)i0 * 64 + (p_) * 8); \
        uint4 v1 = *(const uint4*)((G_) + (size_t)i1 * 64 + (p_) * 8); \
        uint4 v2 = *(const uint4*)((G_) + (size_t)i2 * 64 + (p_) * 8); \
        uint4 v3 = *(const uint4*)((G_) + (size_t)i3 * 64 + (p_) * 8); \
        ACC8H(HA, v0) ACC8H(HA, v1) ACC8H(HA, v2) ACC8H(HA, v3) \
    } \
    for (; e < (end_); e += 2) { \
        int ii = csrc[e]; \
        uint4 v = *(const uint4*)((G_) + (size_t)ii * 64 + (p_) * 8); \
        ACC8H(HA, v) \
    } \
    _Pragma("unroll") \
    for (int q = 0; q < 4; ++q) { \
        int o = __shfl_xor(*(int*)&HA[q], 8); \
        HA[q] = __hadd2(HA[q], *(__half2*)&o); \
    } }

#define CONV_EPILOGUE(G_, d_, dv_, bias_, p_, HA, HOUT) { \
    uint4 sv = *(const uint4*)((G_) + (size_t)(d_) * 64 + (p_) * 8); \
    float4 bb0 = *(const float4*)((bias_) + (p_) * 8); \
    float4 bb1 = *(const float4*)((bias_) + (p_) * 8 + 4); \
    float2 a0 = __half22float2(HA[0]), a1 = __half22float2(HA[1]); \
    float2 a2 = __half22float2(HA[2]), a3 = __half22float2(HA[3]); \
    float2 s0 = __half22float2(*(const __half2*)&sv.x); \
    float2 s1 = __half22float2(*(const __half2*)&sv.y); \
    float2 s2 = __half22float2(*(const __half2*)&sv.z); \
    float2 s3 = __half22float2(*(const __half2*)&sv.w); \
    HOUT[0] = fmaxf((a0.x + s0.x) * (dv_) + bb0.x, 0.f); \
    HOUT[1] = fmaxf((a0.y + s0.y) * (dv_) + bb0.y, 0.f); \
    HOUT[2] = fmaxf((a1.x + s1.x) * (dv_) + bb0.z, 0.f); \
    HOUT[3] = fmaxf((a1.y + s1.y) * (dv_) + bb0.w, 0.f); \
    HOUT[4] = fmaxf((a2.x + s2.x) * (dv_) + bb1.x, 0.f); \
    HOUT[5] = fmaxf((a2.y + s2.y) * (dv_) + bb1.y, 0.f); \
    HOUT[6] = fmaxf((a3.x + s3.x) * (dv_) + bb1.z, 0.f); \
    HOUT[7] = fmaxf((a3.y + s3.y) * (dv_) + bb1.w, 0.f); }

// ---- agg layer1 + MFMA W2: G2[d,:] = fp16((relu(conv1) @ W2) * dinv[d]) ----
// Block = 16 nodes; wave w gathers nodes w*4..+4 CONCURRENTLY (16 lanes each).
__global__ __launch_bounds__(256) void k_agg_mid(const __half* __restrict__ G,
        const int* __restrict__ rofs, const int* __restrict__ csrc,
        const float* __restrict__ dinv, const float* __restrict__ b1,
        const float* __restrict__ W2, __half* __restrict__ G2, int nrows) {
    __shared__ unsigned short W2t[64 * 68];  // bf16 W2^T [col][k]
    __shared__ unsigned short H1s[16 * 68];  // bf16 h1 rows [node][k]
    const int t = threadIdx.x;
    for (int i = t; i < 4096; i += 256) {
        int k = i >> 6, c = i & 63;
        W2t[c * 68 + k] = bf16_1(W2[i]);
    }
    const int l = t & 63;
    const int w = t >> 6;
    const int n = l >> 4;                  // node within wave
    const int s = (l >> 3) & 1;            // edge slot
    const int p = l & 7;                   // feature chunk
    const int row = w * 4 + n;
    const int d = blockIdx.x * 16 + row;
    if (d < nrows) {
        const int beg = rofs[d], end = rofs[d + 1];
        __half2 ha[4];
        #pragma unroll
        for (int q = 0; q < 4; ++q) ha[q] = __half2(__float2half(0.f), __float2half(0.f));
        GATHER16(G, beg, end, s, p, ha)
        float dv = dinv[d];
        float h1[8];
        CONV_EPILOGUE(G, d, dv, b1, p, ha, h1)
        if (s == 0) {
            int4 pk;
            pk.x = cvt2bf(h1[0], h1[1]); pk.y = cvt2bf(h1[2], h1[3]);
            pk.z = cvt2bf(h1[4], h1[5]); pk.w = cvt2bf(h1[6], h1[7]);
            *(int4*)(&H1s[row * 68 + p * 8]) = pk;
        }
    }
    __syncthreads();
    // phase 2: D = H1 @ W2 (16x64), wave w owns cols w*16..+16
    const int c16 = l & 15, g4 = l >> 4;
    const int nbase = blockIdx.x * 16;
    f32x4 acc = {0.f, 0.f, 0.f, 0.f};
    #pragma unroll
    for (int kc = 0; kc < 2; ++kc) {
        bf16x8 a = *(bf16x8*)(&H1s[c16 * 68 + kc * 32 + g4 * 8]);
        bf16x8 b = *(bf16x8*)(&W2t[(w * 16 + c16) * 68 + kc * 32 + g4 * 8]);
        acc = __builtin_amdgcn_mfma_f32_16x16x32_bf16(a, b, acc, 0, 0, 0);
    }
    #pragma unroll
    for (int r = 0; r < 4; ++r) {
        int dd = nbase + g4 * 4 + r;
        if (dd < nrows)
            G2[(size_t)dd * 64 + w * 16 + c16] = __float2half(acc[r] * dinv[dd]);
    }
}

// ---- agg layer2 + MFMA W3 + log_softmax -> out ----
__global__ __launch_bounds__(256) void k_agg_out(const __half* __restrict__ G2,
        const int* __restrict__ rofs, const int* __restrict__ csrc,
        const float* __restrict__ dinv, const float* __restrict__ b2,
        const float* __restrict__ W3, const float* __restrict__ b3,
        float* __restrict__ out, int nrows) {
    constexpr int LP = 49;
    __shared__ unsigned short W3t[48 * 68];  // bf16 W3^T, cols 40..47 zero
    __shared__ unsigned short H2s[16 * 68];
    __shared__ float Ls[16 * LP];
    __shared__ float b3s[48];
    const int t = threadIdx.x;
    for (int i = t; i < 48 * 64; i += 256) {
        int c = i >> 6, k = i & 63;
        W3t[c * 68 + k] = (c < 40) ? bf16_1(W3[k * 40 + c]) : (unsigned short)0;
    }
    if (t < 48) b3s[t] = (t < 40) ? b3[t] : 0.f;
    const int l = t & 63;
    const int w = t >> 6;
    const int n = l >> 4;
    const int s = (l >> 3) & 1;
    const int p = l & 7;
    const int row = w * 4 + n;
    const int d = blockIdx.x * 16 + row;
    if (d < nrows) {
        const int beg = rofs[d], end = rofs[d + 1];
        __half2 ha[4];
        #pragma unroll
        for (int q = 0; q < 4; ++q) ha[q] = __half2(__float2half(0.f), __float2half(0.f));
        GATHER16(G2, beg, end, s, p, ha)
        float dv = dinv[d];
        float h2[8];
        CONV_EPILOGUE(G2, d, dv, b2, p, ha, h2)
        if (s == 0) {
            int4 pk;
            pk.x = cvt2bf(h2[0], h2[1]); pk.y = cvt2bf(h2[2], h2[3]);
            pk.z = cvt2bf(h2[4], h2[5]); pk.w = cvt2bf(h2[6], h2[7]);
            *(int4*)(&H2s[row * 68 + p * 8]) = pk;
        }
    }
    __syncthreads();
    // phase 2: logits = H2 @ W3 (16x40, padded 48); waves 0..2 only
    const int c16 = l & 15, g4 = l >> 4;
    const int nbase = blockIdx.x * 16;
    if (w < 3) {
        f32x4 acc = {0.f, 0.f, 0.f, 0.f};
        #pragma unroll
        for (int kc = 0; kc < 2; ++kc) {
            bf16x8 a = *(bf16x8*)(&H2s[c16 * 68 + kc * 32 + g4 * 8]);
            bf16x8 b = *(bf16x8*)(&W3t[(w * 16 + c16) * 68 + kc * 32 + g4 * 8]);
            acc = __builtin_amdgcn_mfma_f32_16x16x32_bf16(a, b, acc, 0, 0, 0);
        }
        #pragma unroll
        for (int r = 0; r < 4; ++r)
            Ls[(g4 * 4 + r) * LP + w * 16 + c16] = acc[r] + b3s[w * 16 + c16];
    }
    __syncthreads();
    // phase 3: per-node log_softmax over 40 logits; wave w -> nodes w*4..+4
    #pragma unroll 1
    for (int i = 0; i < 4; ++i) {
        int rr = w * 4 + i;
        int dd = nbase + rr;
        if (dd >= nrows) continue;
        float v = (l < 40) ? Ls[rr * LP + l] : -3.4e38f;
        float m = v;
        #pragma unroll
        for (int off = 1; off < 64; off <<= 1) m = fmaxf(m, __shfl_xor(m, off));
        float ex = (l < 40) ? expf(v - m) : 0.f;
        float ssum = ex;
        #pragma unroll
        for (int off = 1; off < 64; off <<= 1) ssum += __shfl_xor(ssum, off);
        float lse = m + logf(ssum);
        if (l < 40) out[(size_t)dd * 40 + l] = v - lse;
    }
}

extern "C" void kernel_launch(void* const* d_in, const int* in_sizes, int n_in,
                              void* d_out, int out_size, void* d_ws, size_t ws_size,
                              hipStream_t stream) {
    const float* x  = (const float*)d_in[0];
    const int*   ei = (const int*)d_in[1];
    const float* W1 = (const float*)d_in[2];
    const float* b1 = (const float*)d_in[3];
    const float* W2 = (const float*)d_in[4];
    const float* b2 = (const float*)d_in[5];
    const float* W3 = (const float*)d_in[6];
    const float* b3 = (const float*)d_in[7];
    float* out = (float*)d_out;

    const int HID = in_sizes[3];            // 64
    const int IND = in_sizes[2] / HID;      // 256
    const int N   = in_sizes[0] / IND;      // 100000
    const int E   = in_sizes[1] / 2;        // 3200000
    (void)HID; (void)n_in; (void)out_size; (void)ws_size;

    const int NBK     = (N + 127) >> 7;             // 782
    const int nchunks = (E + CHUNK - 1) / CHUNK;    // 391

    char* ws = (char*)d_ws;
    size_t off = 0;
    auto alloc = [&](size_t bytes) -> char* {
        char* p = ws + off;
        off = (off + bytes + 255) & ~(size_t)255;
        return p;
    };
    size_t gbytes = (size_t)N * 64 * 2;             // fp16 G
    size_t p1bytes = (size_t)E * 4;                 // pairs1 overlay
    int*      cntMat     = (int*)     alloc((size_t)nchunks * NBK * 4);
    int*      startMat   = (int*)     alloc((size_t)nchunks * NBK * 4);
    int*      TB         = (int*)     alloc((size_t)NBK * 4);
    int*      bucketBase = (int*)     alloc(((size_t)NBK + 1) * 4);
    float*    dinv       = (float*)   alloc((size_t)N * 4);
    int*      rofs       = (int*)     alloc(((size_t)N + 1) * 4);
    int*      csrc       = (int*)     alloc((size_t)E * 4);
    __half*   g          = (__half*)  alloc(gbytes > p1bytes ? gbytes : p1bytes);
    __half*   g2         = (__half*)  alloc(gbytes);
    unsigned* pairs1     = (unsigned*)g;    // overlay: dead before gemm1 writes g

    const int* esrc = ei;
    const int* edst = ei + E;
    const int gM  = (N + 63) / 64;          // 1563
    const int gA  = (N + 15) / 16;          // 6250

    p2_localsort<<<nchunks, 256, 0, stream>>>(esrc, edst, E, pairs1, cntMat, startMat, NBK);
    p3_colscan  <<<NBK, 256, 0, stream>>>(cntMat, TB, nchunks, NBK);
    p4_scan     <<<1, 256, 0, stream>>>(TB, bucketBase, NBK, E);
    p6_sortcsr  <<<NBK, 256, 0, stream>>>(pairs1, cntMat, startMat, TB, bucketBase,
                                          nchunks, NBK, csrc, rofs, dinv, N, E);

    k_gemm<256> <<<gM, 256, 0, stream>>>(x, W1, dinv, g, N);
    k_agg_mid   <<<gA, 256, 0, stream>>>(g, rofs, csrc, dinv, b1, W2, g2, N);
    k_agg_out   <<<gA, 256, 0, stream>>>(g2, rofs, csrc, dinv, b2, W3, b3, out, N);
}

// Round 13
// 275.301 us; speedup vs baseline: 1.3906x; 1.0062x over previous
//
#include <hip/hip_runtime.h>
#include <hip/hip_fp16.h>
#include <cstdint>

// GCN: partition -> CSR; gemm1 (fp32 tile, fp16 out); two fused gather kernels.
// Gather: 512-thr blocks, 2 nodes/wave (32 lanes/node: 4 slots x 8 chunks,
// 4-deep) -> bf16 h-rows in LDS -> 16-node MFMA vs W2 / W3 (+log_softmax).

constexpr int CHUNK = 8192;
constexpr int BKCAP = 8192;

typedef __attribute__((ext_vector_type(8))) short bf16x8;
typedef __attribute__((ext_vector_type(4))) float f32x4;

__device__ __forceinline__ int cvt2bf(float a, float b) {
    int r;
    asm("v_cvt_pk_bf16_f32 %0, %1, %2" : "=v"(r) : "v"(a), "v"(b));
    return r;
}
__device__ __forceinline__ unsigned short bf16_1(float a) {
    return (unsigned short)(cvt2bf(a, a) & 0xFFFF);
}

// ---- P2: per-chunk bucket sort into pairs1 (chunk-grouped, packed 4B) ----
__global__ __launch_bounds__(256) void p2_localsort(
        const int* __restrict__ esrc, const int* __restrict__ edst, int E,
        unsigned* __restrict__ pairs1, int* __restrict__ cntMat,
        int* __restrict__ startMat, int NBK) {
    __shared__ int hist[1024];
    __shared__ int wsum[256];
    __shared__ unsigned lp[CHUNK];
    const int t = threadIdx.x, blk = blockIdx.x;
    const int base = blk * CHUNK;
    const int cnt = min(CHUNK, E - base);
    for (int i = t; i < 1024; i += 256) hist[i] = 0;
    __syncthreads();
    for (int i = t; i < cnt; i += 256) atomicAdd(&hist[edst[base + i] >> 7], 1);
    __syncthreads();
    int h0 = hist[4*t], h1 = hist[4*t+1], h2 = hist[4*t+2], h3 = hist[4*t+3];
    int s = h0 + h1 + h2 + h3;
    wsum[t] = s; __syncthreads();
    #pragma unroll
    for (int o = 1; o < 256; o <<= 1) {
        int x = (t >= o) ? wsum[t - o] : 0;
        __syncthreads(); wsum[t] += x; __syncthreads();
    }
    int run = wsum[t] - s;
    int e0 = run, e1 = run + h0, e2 = e1 + h1, e3 = e2 + h2;
    hist[4*t] = e0; hist[4*t+1] = e1; hist[4*t+2] = e2; hist[4*t+3] = e3;
    if (4*t     < NBK) { cntMat[(size_t)blk*NBK + 4*t]     = h0; startMat[(size_t)blk*NBK + 4*t]     = e0; }
    if (4*t + 1 < NBK) { cntMat[(size_t)blk*NBK + 4*t + 1] = h1; startMat[(size_t)blk*NBK + 4*t + 1] = e1; }
    if (4*t + 2 < NBK) { cntMat[(size_t)blk*NBK + 4*t + 2] = h2; startMat[(size_t)blk*NBK + 4*t + 2] = e2; }
    if (4*t + 3 < NBK) { cntMat[(size_t)blk*NBK + 4*t + 3] = h3; startMat[(size_t)blk*NBK + 4*t + 3] = e3; }
    __syncthreads();
    for (int i = t; i < cnt; i += 256) {
        int d = edst[base + i];
        int pos = atomicAdd(&hist[d >> 7], 1);
        lp[pos] = ((unsigned)(d & 127) << 17) | (unsigned)esrc[base + i];
    }
    __syncthreads();
    for (int i = t; i < cnt; i += 256) pairs1[base + i] = lp[i];
}

// ---- P3: column-wise exclusive scan of cntMat over chunks; totals -> TB ----
__global__ __launch_bounds__(256) void p3_colscan(int* __restrict__ cntMat,
        int* __restrict__ TB, int nchunks, int NBK) {
    __shared__ int buf[512];
    const int t = threadIdx.x, b = blockIdx.x;
    int v0 = (t < nchunks) ? cntMat[(size_t)t*NBK + b] : 0;
    int v1 = (t + 256 < nchunks) ? cntMat[(size_t)(t + 256)*NBK + b] : 0;
    buf[t] = v0; buf[t + 256] = v1; __syncthreads();
    #pragma unroll
    for (int o = 1; o < 512; o <<= 1) {
        int x0 = (t >= o) ? buf[t - o] : 0;
        int x1 = (t + 256 >= o) ? buf[t + 256 - o] : 0;
        __syncthreads(); buf[t] += x0; buf[t + 256] += x1; __syncthreads();
    }
    if (t < nchunks) cntMat[(size_t)t*NBK + b] = buf[t] - v0;
    if (t + 256 < nchunks) cntMat[(size_t)(t + 256)*NBK + b] = buf[t + 256] - v1;
    if (t == 0) TB[b] = buf[511];
}

// ---- P4: exclusive scan of TB -> bucketBase ----
__global__ __launch_bounds__(256) void p4_scan(const int* __restrict__ TB,
        int* __restrict__ bucketBase, int NBK, int E) {
    __shared__ int buf[1024];
    __shared__ int wsum[256];
    const int t = threadIdx.x;
    for (int i = t; i < 1024; i += 256) buf[i] = (i < NBK) ? TB[i] : 0;
    __syncthreads();
    int h0 = buf[4*t], h1 = buf[4*t+1], h2 = buf[4*t+2], h3 = buf[4*t+3];
    int s = h0 + h1 + h2 + h3;
    wsum[t] = s; __syncthreads();
    #pragma unroll
    for (int o = 1; o < 256; o <<= 1) {
        int x = (t >= o) ? wsum[t - o] : 0;
        __syncthreads(); wsum[t] += x; __syncthreads();
    }
    int run = wsum[t] - s;
    int e0 = run, e1 = run + h0, e2 = e1 + h1, e3 = e2 + h2;
    if (4*t     < NBK) bucketBase[4*t]     = e0;
    if (4*t + 1 < NBK) bucketBase[4*t + 1] = e1;
    if (4*t + 2 < NBK) bucketBase[4*t + 2] = e2;
    if (4*t + 3 < NBK) bucketBase[4*t + 3] = e3;
    if (t == 0) bucketBase[NBK] = E;
}

// ---- P6: per-bucket gather + LDS counting-sort -> csrc/rofs/dinv ----
__global__ __launch_bounds__(256) void p6_sortcsr(
        const unsigned* __restrict__ pairs1, const int* __restrict__ cumMat,
        const int* __restrict__ startMat, const int* __restrict__ TB,
        const int* __restrict__ bucketBase, int nchunks, int NBK,
        int* __restrict__ csrc, int* __restrict__ rofs,
        float* __restrict__ dinv, int N, int E) {
    __shared__ unsigned lp[BKCAP];
    __shared__ int ccum[512];
    __shared__ int cstart[512];
    __shared__ int hist[128];
    __shared__ int sc[128];
    __shared__ int foffs[128];
    const int t = threadIdx.x, b = blockIdx.x;
    const int total0 = TB[b];
    const int total = min(total0, BKCAP);
    const int base = bucketBase[b];
    for (int i = t; i < nchunks; i += 256) {
        ccum[i]   = cumMat[(size_t)i * NBK + b];
        cstart[i] = startMat[(size_t)i * NBK + b];
    }
    if (t < 128) hist[t] = 0;
    if (t == 0) ccum[nchunks] = total0;
    __syncthreads();
    for (int i = t; i < total; i += 256) {
        int lo = 0, hi = nchunks - 1;
        while (lo < hi) {
            int mid = (lo + hi + 1) >> 1;
            if (ccum[mid] <= i) lo = mid; else hi = mid - 1;
        }
        unsigned v = pairs1[(size_t)lo * CHUNK + cstart[lo] + (i - ccum[lo])];
        lp[i] = v;
        atomicAdd(&hist[v >> 17], 1);
    }
    __syncthreads();
    if (t < 128) sc[t] = hist[t];
    __syncthreads();
    #pragma unroll
    for (int o = 1; o < 128; o <<= 1) {
        int x = (t >= o && t < 128) ? sc[t - o] : 0;
        __syncthreads();
        if (t < 128) sc[t] += x;
        __syncthreads();
    }
    if (t < 128) {
        int excl = sc[t] - hist[t];
        foffs[t] = excl;
        int node = b * 128 + t;
        if (node < N) {
            rofs[node] = base + excl;
            dinv[node] = rsqrtf((float)hist[t] + 1.0f);
        }
    }
    if (b == 0 && t == 255) rofs[N] = E;
    __syncthreads();
    for (int i = t; i < total; i += 256) {
        unsigned v = lp[i];
        int pos = atomicAdd(&foffs[v >> 17], 1);
        csrc[base + pos] = (int)(v & 0x1FFFFu);
    }
}

// ---- GEMM1 (proven r7): G[row,:] = fp16((X @ W1) * dinv), fp32 vector ----
template<int K>
__global__ __launch_bounds__(256) void k_gemm(const float* __restrict__ X,
        const float* __restrict__ Wm, const float* __restrict__ dinv,
        __half* __restrict__ G, int nrows) {
    constexpr int BK = 32;
    constexpr int NCH = K / BK;
    constexpr int XP = 68;
    __shared__ float Xs[BK * XP];
    __shared__ float Ws[BK * 64];
    const int t = threadIdx.x;
    const int cg = t & 15;
    const int rg = t >> 4;
    const int brow = blockIdx.x * 64;

    float acc[4][4];
    #pragma unroll
    for (int r = 0; r < 4; ++r)
        #pragma unroll
        for (int c = 0; c < 4; ++c) acc[r][c] = 0.f;

    for (int ch = 0; ch < NCH; ++ch) {
        if (ch) __syncthreads();
        #pragma unroll
        for (int i = 0; i < 2; ++i) {
            int f = t + i * 256;
            int r = f >> 3, c4 = f & 7;
            int gr = brow + r;
            float4 v = make_float4(0.f, 0.f, 0.f, 0.f);
            if (gr < nrows)
                v = *(const float4*)(X + (size_t)gr * K + ch * BK + c4 * 4);
            int rsw = r ^ (c4 << 2);
            Xs[(c4 * 4 + 0) * XP + rsw] = v.x;
            Xs[(c4 * 4 + 1) * XP + rsw] = v.y;
            Xs[(c4 * 4 + 2) * XP + rsw] = v.z;
            Xs[(c4 * 4 + 3) * XP + rsw] = v.w;
        }
        #pragma unroll
        for (int i = 0; i < 2; ++i) {
            int f = t + i * 256;
            int k = f >> 4, c4 = f & 15;
            *(float4*)(Ws + k * 64 + c4 * 4) =
                *(const float4*)(Wm + (size_t)(ch * BK + k) * 64 + c4 * 4);
        }
        __syncthreads();

        #pragma unroll
        for (int k = 0; k < BK; ++k) {
            const int xsw = (k >> 2) << 2;
            float4 xa = *(const float4*)(Xs + k * XP + ((rg * 4) ^ xsw));
            float4 wv = *(const float4*)(Ws + k * 64 + cg * 4);
            acc[0][0] += xa.x * wv.x; acc[0][1] += xa.x * wv.y;
            acc[0][2] += xa.x * wv.z; acc[0][3] += xa.x * wv.w;
            acc[1][0] += xa.y * wv.x; acc[1][1] += xa.y * wv.y;
            acc[1][2] += xa.y * wv.z; acc[1][3] += xa.y * wv.w;
            acc[2][0] += xa.z * wv.x; acc[2][1] += xa.z * wv.y;
            acc[2][2] += xa.z * wv.z; acc[2][3] += xa.z * wv.w;
            acc[3][0] += xa.w * wv.x; acc[3][1] += xa.w * wv.y;
            acc[3][2] += xa.w * wv.z; acc[3][3] += xa.w * wv.w;
        }
    }
    #pragma unroll
    for (int r = 0; r < 4; ++r) {
        int gr = brow + rg * 4 + r;
        if (gr < nrows) {
            float dv = dinv[gr];
            __half2 h01 = __floats2half2_rn(acc[r][0] * dv, acc[r][1] * dv);
            __half2 h23 = __floats2half2_rn(acc[r][2] * dv, acc[r][3] * dv);
            uint2 pk;
            pk.x = *(unsigned*)&h01; pk.y = *(unsigned*)&h23;
            *(uint2*)(G + (size_t)gr * 64 + cg * 4) = pk;
        }
    }
}

// ---- gather helpers ----
#define ACC8H(HA, V) { \
    HA[0] = __hadd2(HA[0], *(const __half2*)&(V).x); \
    HA[1] = __hadd2(HA[1], *(const __half2*)&(V).y); \
    HA[2] = __hadd2(HA[2], *(const __half2*)&(V).z); \
    HA[3] = __hadd2(HA[3], *(const __half2*)&(V).w); }

// 32 lanes per node: 4 slots x 8 chunks, 4-deep unroll (16 edges/node in
// flight). deg=32 -> exactly 2 main iterations, no tail. Combine slots via
// shfl_xor(8) + shfl_xor(16) (stays within the 32-lane node group).
#define GATHER32(G_, beg_, end_, s_, p_, HA) { \
    int e = (beg_) + (s_); \
    for (; e + 12 < (end_); e += 16) { \
        int i0 = csrc[e], i1 = csrc[e + 4], i2 = csrc[e + 8], i3 = csrc[e + 12]; \
        uint4 v0 = *(const uint4*)((G_) + (size_t)i0 * 64 + (p_) * 8); \
        uint4 v1 = *(const uint4*)((G_) + (size_t)i1 * 64 + (p_) * 8); \
        uint4 v2 = *(const uint4*)((G_) + (size_t)i2 * 64 + (p_) * 8); \
        uint4 v3 = *(const uint4*)((G_) + (size_t)i3 * 64 + (p_) * 8); \
        ACC8H(HA, v0) ACC8H(HA, v1) ACC8H(HA, v2) ACC8H(HA, v3) \
    } \
    for (; e < (end_); e += 4) { \
        int ii = csrc[e]; \
        uint4 v = *(const uint4*)((G_) + (size_t)ii * 64 + (p_) * 8); \
        ACC8H(HA, v) \
    } \
    _Pragma("unroll") \
    for (int q = 0; q < 4; ++q) { \
        int o = __shfl_xor(*(int*)&HA[q], 8); \
        HA[q] = __hadd2(HA[q], *(__half2*)&o); \
        o = __shfl_xor(*(int*)&HA[q], 16); \
        HA[q] = __hadd2(HA[q], *(__half2*)&o); \
    } }

#define CONV_EPILOGUE(G_, d_, dv_, bias_, p_, HA, HOUT) { \
    uint4 sv = *(const uint4*)((G_) + (size_t)(d_) * 64 + (p_) * 8); \
    float4 bb0 = *(const float4*)((bias_) + (p_) * 8); \
    float4 bb1 = *(const float4*)((bias_) + (p_) * 8 + 4); \
    float2 a0 = __half22float2(HA[0]), a1 = __half22float2(HA[1]); \
    float2 a2 = __half22float2(HA[2]), a3 = __half22float2(HA[3]); \
    float2 s0 = __half22float2(*(const __half2*)&sv.x); \
    float2 s1 = __half22float2(*(const __half2*)&sv.y); \
    float2 s2 = __half22float2(*(const __half2*)&sv.z); \
    float2 s3 = __half22float2(*(const __half2*)&sv.w); \
    HOUT[0] = fmaxf((a0.x + s0.x) * (dv_) + bb0.x, 0.f); \
    HOUT[1] = fmaxf((a0.y + s0.y) * (dv_) + bb0.y, 0.f); \
    HOUT[2] = fmaxf((a1.x + s1.x) * (dv_) + bb0.z, 0.f); \
    HOUT[3] = fmaxf((a1.y + s1.y) * (dv_) + bb0.w, 0.f); \
    HOUT[4] = fmaxf((a2.x + s2.x) * (dv_) + bb1.x, 0.f); \
    HOUT[5] = fmaxf((a2.y + s2.y) * (dv_) + bb1.y, 0.f); \
    HOUT[6] = fmaxf((a3.x + s3.x) * (dv_) + bb1.z, 0.f); \
    HOUT[7] = fmaxf((a3.y + s3.y) * (dv_) + bb1.w, 0.f); }

// ---- agg layer1 + MFMA W2: G2[d,:] = fp16((relu(conv1) @ W2) * dinv[d]) ----
// Block = 512 thr = 8 waves = 16 nodes; wave w gathers nodes 2w, 2w+1.
__global__ __launch_bounds__(512) void k_agg_mid(const __half* __restrict__ G,
        const int* __restrict__ rofs, const int* __restrict__ csrc,
        const float* __restrict__ dinv, const float* __restrict__ b1,
        const float* __restrict__ W2, __half* __restrict__ G2, int nrows) {
    __shared__ unsigned short W2t[64 * 68];  // bf16 W2^T [col][k]
    __shared__ unsigned short H1s[16 * 68];  // bf16 h1 rows [node][k]
    const int t = threadIdx.x;
    for (int i = t; i < 4096; i += 512) {
        int k = i >> 6, c = i & 63;
        W2t[c * 68 + k] = bf16_1(W2[i]);
    }
    const int l = t & 63;
    const int w = t >> 6;                  // wave 0..7
    const int n = l >> 5;                  // node within wave (0..1)
    const int s = (l >> 3) & 3;            // edge slot (0..3)
    const int p = l & 7;                   // feature chunk
    const int row = w * 2 + n;
    const int d = blockIdx.x * 16 + row;
    if (d < nrows) {
        const int beg = rofs[d], end = rofs[d + 1];
        __half2 ha[4];
        #pragma unroll
        for (int q = 0; q < 4; ++q) ha[q] = __half2(__float2half(0.f), __float2half(0.f));
        GATHER32(G, beg, end, s, p, ha)
        float dv = dinv[d];
        float h1[8];
        CONV_EPILOGUE(G, d, dv, b1, p, ha, h1)
        if (s == 0) {
            int4 pk;
            pk.x = cvt2bf(h1[0], h1[1]); pk.y = cvt2bf(h1[2], h1[3]);
            pk.z = cvt2bf(h1[4], h1[5]); pk.w = cvt2bf(h1[6], h1[7]);
            *(int4*)(&H1s[row * 68 + p * 8]) = pk;
        }
    }
    __syncthreads();
    // phase 2: D = H1 @ W2 (16x64); waves 0..3 own cols w*16..+16
    const int c16 = l & 15, g4 = l >> 4;
    const int nbase = blockIdx.x * 16;
    if (w < 4) {
        f32x4 acc = {0.f, 0.f, 0.f, 0.f};
        #pragma unroll
        for (int kc = 0; kc < 2; ++kc) {
            bf16x8 a = *(bf16x8*)(&H1s[c16 * 68 + kc * 32 + g4 * 8]);
            bf16x8 b = *(bf16x8*)(&W2t[(w * 16 + c16) * 68 + kc * 32 + g4 * 8]);
            acc = __builtin_amdgcn_mfma_f32_16x16x32_bf16(a, b, acc, 0, 0, 0);
        }
        #pragma unroll
        for (int r = 0; r < 4; ++r) {
            int dd = nbase + g4 * 4 + r;
            if (dd < nrows)
                G2[(size_t)dd * 64 + w * 16 + c16] = __float2half(acc[r] * dinv[dd]);
        }
    }
}

// ---- agg layer2 + MFMA W3 + log_softmax -> out ----
__global__ __launch_bounds__(512) void k_agg_out(const __half* __restrict__ G2,
        const int* __restrict__ rofs, const int* __restrict__ csrc,
        const float* __restrict__ dinv, const float* __restrict__ b2,
        const float* __restrict__ W3, const float* __restrict__ b3,
        float* __restrict__ out, int nrows) {
    constexpr int LP = 49;
    __shared__ unsigned short W3t[48 * 68];  // bf16 W3^T, cols 40..47 zero
    __shared__ unsigned short H2s[16 * 68];
    __shared__ float Ls[16 * LP];
    __shared__ float b3s[48];
    const int t = threadIdx.x;
    for (int i = t; i < 48 * 64; i += 512) {
        int c = i >> 6, k = i & 63;
        W3t[c * 68 + k] = (c < 40) ? bf16_1(W3[k * 40 + c]) : (unsigned short)0;
    }
    if (t < 48) b3s[t] = (t < 40) ? b3[t] : 0.f;
    const int l = t & 63;
    const int w = t >> 6;
    const int n = l >> 5;
    const int s = (l >> 3) & 3;
    const int p = l & 7;
    const int row = w * 2 + n;
    const int d = blockIdx.x * 16 + row;
    if (d < nrows) {
        const int beg = rofs[d], end = rofs[d + 1];
        __half2 ha[4];
        #pragma unroll
        for (int q = 0; q < 4; ++q) ha[q] = __half2(__float2half(0.f), __float2half(0.f));
        GATHER32(G2, beg, end, s, p, ha)
        float dv = dinv[d];
        float h2[8];
        CONV_EPILOGUE(G2, d, dv, b2, p, ha, h2)
        if (s == 0) {
            int4 pk;
            pk.x = cvt2bf(h2[0], h2[1]); pk.y = cvt2bf(h2[2], h2[3]);
            pk.z = cvt2bf(h2[4], h2[5]); pk.w = cvt2bf(h2[6], h2[7]);
            *(int4*)(&H2s[row * 68 + p * 8]) = pk;
        }
    }
    __syncthreads();
    // phase 2: logits = H2 @ W3 (16x40, padded 48); waves 0..2 only
    const int c16 = l & 15, g4 = l >> 4;
    const int nbase = blockIdx.x * 16;
    if (w < 3) {
        f32x4 acc = {0.f, 0.f, 0.f, 0.f};
        #pragma unroll
        for (int kc = 0; kc < 2; ++kc) {
            bf16x8 a = *(bf16x8*)(&H2s[c16 * 68 + kc * 32 + g4 * 8]);
            bf16x8 b = *(bf16x8*)(&W3t[(w * 16 + c16) * 68 + kc * 32 + g4 * 8]);
            acc = __builtin_amdgcn_mfma_f32_16x16x32_bf16(a, b, acc, 0, 0, 0);
        }
        #pragma unroll
        for (int r = 0; r < 4; ++r)
            Ls[(g4 * 4 + r) * LP + w * 16 + c16] = acc[r] + b3s[w * 16 + c16];
    }
    __syncthreads();
    // phase 3: per-node log_softmax over 40 logits; wave w -> nodes 2w, 2w+1
    #pragma unroll 1
    for (int i = 0; i < 2; ++i) {
        int rr = w * 2 + i;
        int dd = nbase + rr;
        if (dd >= nrows) continue;
        float v = (l < 40) ? Ls[rr * LP + l] : -3.4e38f;
        float m = v;
        #pragma unroll
        for (int off = 1; off < 64; off <<= 1) m = fmaxf(m, __shfl_xor(m, off));
        float ex = (l < 40) ? expf(v - m) : 0.f;
        float ssum = ex;
        #pragma unroll
        for (int off = 1; off < 64; off <<= 1) ssum += __shfl_xor(ssum, off);
        float lse = m + logf(ssum);
        if (l < 40) out[(size_t)dd * 40 + l] = v - lse;
    }
}

extern "C" void kernel_launch(void* const* d_in, const int* in_sizes, int n_in,
                              void* d_out, int out_size, void* d_ws, size_t ws_size,
                              hipStream_t stream) {
    const float* x  = (const float*)d_in[0];
    const int*   ei = (const int*)d_in[1];
    const float* W1 = (const float*)d_in[2];
    const float* b1 = (const float*)d_in[3];
    const float* W2 = (const float*)d_in[4];
    const float* b2 = (const float*)d_in[5];
    const float* W3 = (const float*)d_in[6];
    const float* b3 = (const float*)d_in[7];
    float* out = (float*)d_out;

    const int HID = in_sizes[3];            // 64
    const int IND = in_sizes[2] / HID;      // 256
    const int N   = in_sizes[0] / IND;      // 100000
    const int E   = in_sizes[1] / 2;        // 3200000
    (void)HID; (void)n_in; (void)out_size; (void)ws_size;

    const int NBK     = (N + 127) >> 7;             // 782
    const int nchunks = (E + CHUNK - 1) / CHUNK;    // 391

    char* ws = (char*)d_ws;
    size_t off = 0;
    auto alloc = [&](size_t bytes) -> char* {
        char* p = ws + off;
        off = (off + bytes + 255) & ~(size_t)255;
        return p;
    };
    size_t gbytes = (size_t)N * 64 * 2;             // fp16 G
    size_t p1bytes = (size_t)E * 4;                 // pairs1 overlay
    int*      cntMat     = (int*)     alloc((size_t)nchunks * NBK * 4);
    int*      startMat   = (int*)     alloc((size_t)nchunks * NBK * 4);
    int*      TB         = (int*)     alloc((size_t)NBK * 4);
    int*      bucketBase = (int*)     alloc(((size_t)NBK + 1) * 4);
    float*    dinv       = (float*)   alloc((size_t)N * 4);
    int*      rofs       = (int*)     alloc(((size_t)N + 1) * 4);
    int*      csrc       = (int*)     alloc((size_t)E * 4);
    __half*   g          = (__half*)  alloc(gbytes > p1bytes ? gbytes : p1bytes);
    __half*   g2         = (__half*)  alloc(gbytes);
    unsigned* pairs1     = (unsigned*)g;    // overlay: dead before gemm1 writes g

    const int* esrc = ei;
    const int* edst = ei + E;
    const int gM  = (N + 63) / 64;          // 1563
    const int gA  = (N + 15) / 16;          // 6250

    p2_localsort<<<nchunks, 256, 0, stream>>>(esrc, edst, E, pairs1, cntMat, startMat, NBK);
    p3_colscan  <<<NBK, 256, 0, stream>>>(cntMat, TB, nchunks, NBK);
    p4_scan     <<<1, 256, 0, stream>>>(TB, bucketBase, NBK, E);
    p6_sortcsr  <<<NBK, 256, 0, stream>>>(pairs1, cntMat, startMat, TB, bucketBase,
                                          nchunks, NBK, csrc, rofs, dinv, N, E);

    k_gemm<256> <<<gM, 256, 0, stream>>>(x, W1, dinv, g, N);
    k_agg_mid   <<<gA, 512, 0, stream>>>(g, rofs, csrc, dinv, b1, W2, g2, N);
    k_agg_out   <<<gA, 512, 0, stream>>>(g2, rofs, csrc, dinv, b2, W3, b3, out, N);
}